// Round 8
// baseline (325.145 us; speedup 1.0000x reference)
//
#include <hip/hip_runtime.h>
#include <hip/hip_bf16.h>

typedef __bf16 bf16x8 __attribute__((ext_vector_type(8)));
typedef float f32x4 __attribute__((ext_vector_type(4)));

#define IN_DIM 256
#define NT 8

__device__ __forceinline__ float b2f(unsigned short u) {
  union { unsigned int i; float f; } x; x.i = ((unsigned int)u) << 16; return x.f;
}
__device__ __forceinline__ float lo2f(unsigned int w) {
  union { unsigned int i; float f; } x; x.i = w << 16; return x.f;
}
__device__ __forceinline__ float hi2f(unsigned int w) {
  union { unsigned int i; float f; } x; x.i = w & 0xFFFF0000u; return x.f;
}
__device__ __forceinline__ unsigned short f2b(float f) {
  union { float f; unsigned int i; } u; u.f = f;
  unsigned int r = u.i + 0x7FFF + ((u.i >> 16) & 1);
  return (unsigned short)(r >> 16);
}
__device__ __forceinline__ float lrelu(float x) { return x >= 0.f ? x : 0.2f * x; }
__device__ __forceinline__ float ldf(const void* p, size_t i, int isf32) {
  return isf32 ? ((const float*)p)[i] : b2f(((const unsigned short*)p)[i]);
}

// ---------- fused prep: [0,384) W-transpose; [384,448) fold a2; [448,454) he/aD;
// [454, 454+ECB) edge count (4 edges/thread). Each prep block self-detects dtype. ----------
__global__ void prep_all_kernel(const void* __restrict__ W1, const void* __restrict__ W2,
                                const void* __restrict__ rW2,
                                const void* __restrict__ al1, const void* __restrict__ ar1,
                                const void* __restrict__ al2, const void* __restrict__ ar2,
                                const void* __restrict__ ee1, const void* __restrict__ Wr1,
                                const void* __restrict__ ae1,
                                const void* __restrict__ ee2, const void* __restrict__ Wr2,
                                const void* __restrict__ ae2,
                                unsigned short* __restrict__ W1t,
                                unsigned short* __restrict__ W2t,
                                float* __restrict__ a2l, float* __restrict__ a2r,
                                float* __restrict__ he1, float* __restrict__ he2,
                                float* __restrict__ alD, float* __restrict__ arD,
                                const unsigned int* __restrict__ hw,
                                const int* __restrict__ col, int* __restrict__ cnt,
                                int E_, int N_, int* __restrict__ dflag) {
  int b = blockIdx.x, tid = threadIdx.x;
  if (b >= 454) {
    // edge-count role (CSR histogram), 4 edges/thread
    int base = (b - 454) * 1024 + tid;
#pragma unroll
    for (int k = 0; k < 4; k++) {
      int e = base + k * 256;
      if (e < E_) {
        int c = col[e];
        if ((unsigned)c < (unsigned)N_) atomicAdd(&cnt[c], 1);
      }
    }
    return;
  }
  // self-detect dtype of h (wave 0 only, broadcast via LDS)
  __shared__ int sflag;
  {
    int bad = 0;
    if (tid < 64) {
      for (int i = 0; i < 4; i++) {
        unsigned int w = hw[tid * 4 + i];
        unsigned int ex = (w & 0x7FFFu) >> 7;
        if (ex >= 0xC0u) bad++;
      }
#pragma unroll
      for (int off = 32; off; off >>= 1) bad += __shfl_xor(bad, off);
      if (tid == 0) sflag = (bad > 8) ? 1 : 0;
    }
    __syncthreads();
  }
  const int isf32 = sflag;
  if (b == 0 && tid == 0) *dflag = isf32;
  if (b < 384) {
    int j = b, k = tid;
    if (j < 256) {
      int src = (j & 3) * 64 + (j >> 2);          // h*64+d
      W1t[j * 256 + k] = f2b(ldf(W1, (size_t)k * 256 + src, isf32));
    } else {
      int o = j - 256;
      float v = (o < 64) ? ldf(W2, (size_t)k * 64 + o, isf32)
                         : ldf(rW2, (size_t)k * 64 + (o - 64), isf32);
      W2t[o * 256 + k] = f2b(v);
    }
  } else if (b < 448) {
    int k = (b - 384) * 4 + (tid >> 6), d = tid & 63;
    float w2 = ldf(W2, (size_t)k * 64 + d, isf32);
    float l2 = w2 * ldf(al2, d, isf32);
    float r2 = w2 * ldf(ar2, d, isf32);
#pragma unroll
    for (int off = 32; off; off >>= 1) { l2 += __shfl_xor(l2, off); r2 += __shfl_xor(r2, off); }
    if (d == 0) { a2l[k] = l2; a2r[k] = r2; }
  } else {
    int bid = b - 448;
    int t = tid >> 5, d = tid & 31;
    if (bid < 4) {
      int h = bid;
      float s = 0.f;
#pragma unroll
      for (int e = 0; e < 32; e++)
        s += ldf(ee1, t * 32 + e, isf32) * ldf(Wr1, (size_t)(t * 32 + e) * 128 + h * 32 + d, isf32);
      float v = s * ldf(ae1, h * 32 + d, isf32);
#pragma unroll
      for (int off = 16; off; off >>= 1) v += __shfl_xor(v, off);
      if (d == 0) he1[t * 4 + h] = v;
    } else if (bid == 4) {
      float s = 0.f;
#pragma unroll
      for (int e = 0; e < 32; e++)
        s += ldf(ee2, t * 32 + e, isf32) * ldf(Wr2, (size_t)(t * 32 + e) * 32 + d, isf32);
      float v = s * ldf(ae2, d, isf32);
#pragma unroll
      for (int off = 16; off; off >>= 1) v += __shfl_xor(v, off);
      if (d == 0) he2[t] = v;
    } else {
      int j = tid;                       // D-major a vectors
      alD[j] = ldf(al1, (j & 3) * 64 + (j >> 2), isf32);
      arD[j] = ldf(ar1, (j & 3) * 64 + (j >> 2), isf32);
    }
  }
}

// ---------- L1 GEMM + CSR-fill in one dispatch (fill role FIRST, blocks [0,FillBlocks)).
// Round-6 structure (BK=64, 48KB LDS, 2 blocks/CU, 2 barriers/chunk) + REGISTER
// DOUBLE-BUFFER: loads for chunk k+1 are issued right after the stage barrier and
// stay in flight across the whole MFMA phase (round-4/5/7 A/B: all-pipes-idle +
// 1.9 TB/s = exposed HBM latency; occupancy alone didn't fix it, and L2-direct B
// put latency inside the MFMA phase). Same barrier count, +~48 VGPR. ----------
__global__ __launch_bounds__(256, 2) void gemm1_fill(
    const void* __restrict__ A, int M,
    const unsigned short* __restrict__ Bt,      // W1t [256][256]
    unsigned short* __restrict__ emb1,
    const float* __restrict__ alD, const float* __restrict__ arD,
    float* __restrict__ hl1, float* __restrict__ hr1,
    const int* __restrict__ dflag, int FillBlocks,
    const int* __restrict__ col, const int* __restrict__ row,
    const int* __restrict__ ety, const int* __restrict__ ptrb,
    const int* __restrict__ bsum, int* __restrict__ cnt,
    int* __restrict__ srcc, int E_) {
  __shared__ unsigned short As[64 * 64];        // 8 KB
  __shared__ unsigned short Bs[256 * 64];       // 32 KB
  __shared__ float lsum[4][64][4];              // 4 KB
  __shared__ float rsum[4][64][4];              // 4 KB
  if (blockIdx.x < FillBlocks) {
    int base = blockIdx.x * 1024 + threadIdx.x;
#pragma unroll
    for (int k = 0; k < 4; k++) {
      int e = base + k * 256;
      if (e < E_) {
        int c = col[e];
        if ((unsigned)c < (unsigned)M) {
          int pos = atomicSub(&cnt[c], 1) - 1;
          long long slot = (long long)(ptrb[c] + bsum[c >> 8]) + pos;
          if (slot >= 0 && slot < E_) {
            int sr = row[e], t = ety[e];
            srcc[slot] = ((unsigned)sr < (unsigned)M && (unsigned)t < (unsigned)NT)
                             ? (sr | (t << 20)) : -1;
          }
        }
      }
    }
    return;
  }
  int isf32 = *dflag;
  const int tid = threadIdx.x;
  const int m0 = (blockIdx.x - FillBlocks) * 64;
  const int wv = tid >> 6, lane = tid & 63;
  const int q = lane >> 4, m = lane & 15;
  const int jp = wv * 64;
  const int arow = tid >> 2, aqt = tid & 3;
  const int gr = m0 + arow;
  f32x4 acc[4][4] = {};
  int4 aR[4];                                   // raw A chunk (f32: 64B; bf16: [0..1])
  int4 bR[8];                                   // B chunk 128B
  aR[0] = aR[1] = aR[2] = aR[3] = (int4){0, 0, 0, 0};

  auto loadA = [&](int kc) {
    if (gr < M) {
      if (isf32) {
        const float* ap = (const float*)A + (size_t)gr * 256 + kc + aqt * 16;
        aR[0] = *(const int4*)ap;
        aR[1] = *(const int4*)(ap + 4);
        aR[2] = *(const int4*)(ap + 8);
        aR[3] = *(const int4*)(ap + 12);
      } else {
        const unsigned short* ap = (const unsigned short*)A + (size_t)gr * 256 + kc + aqt * 16;
        aR[0] = *(const int4*)ap;
        aR[1] = *(const int4*)(ap + 8);
      }
    }
  };
  auto loadB = [&](int kc) {
#pragma unroll
    for (int i = 0; i < 8; i++) {
      int id = tid + i * 256;
      int brow = id >> 3, bg = id & 7;
      bR[i] = *(const int4*)(Bt + (size_t)brow * 256 + kc + bg * 8);
    }
  };

  loadA(0); loadB(0);
  for (int kc = 0; kc < 256; kc += 64) {
    {   // stage regs -> LDS (with f32->bf16 convert on the A path)
      unsigned short tmp[16];
      if (isf32) {
        const float* f = (const float*)aR;
#pragma unroll
        for (int x = 0; x < 16; x++) tmp[x] = f2b(f[x]);
      } else {
        *(int4*)tmp = aR[0];
        *(int4*)(tmp + 8) = aR[1];
      }
      int g0 = (aqt * 2) ^ (arow & 7);
      int g1 = (aqt * 2 + 1) ^ (arow & 7);
      *(int4*)(As + arow * 64 + g0 * 8) = *(int4*)tmp;
      *(int4*)(As + arow * 64 + g1 * 8) = *(int4*)(tmp + 8);
#pragma unroll
      for (int i = 0; i < 8; i++) {
        int id = tid + i * 256;
        int brow = id >> 3, bg = id & 7;
        int pg = bg ^ (brow & 7);
        *(int4*)(Bs + brow * 64 + pg * 8) = bR[i];
      }
    }
    __syncthreads();
    if (kc < 192) { loadA(kc + 64); loadB(kc + 64); }   // in flight across MFMA phase
#pragma unroll
    for (int ks = 0; ks < 2; ks++) {
      int gk = ks * 4 + q;
      bf16x8 afr[4];
#pragma unroll
      for (int cm = 0; cm < 4; cm++) {
        int row_ = cm * 16 + m;
        afr[cm] = *(const bf16x8*)(As + row_ * 64 + (gk ^ (row_ & 7)) * 8);
      }
#pragma unroll
      for (int cj = 0; cj < 4; cj++) {
        int jr = jp + cj * 16 + m;
        bf16x8 b = *(const bf16x8*)(Bs + jr * 64 + (gk ^ (jr & 7)) * 8);
#pragma unroll
        for (int cm = 0; cm < 4; cm++)
          acc[cm][cj] = __builtin_amdgcn_mfma_f32_16x16x32_bf16(afr[cm], b, acc[cm][cj], 0, 0, 0);
      }
    }
    __syncthreads();
  }
  float al[4], ar[4];
#pragma unroll
  for (int cj = 0; cj < 4; cj++) {
    al[cj] = alD[jp + cj * 16 + m];
    ar[cj] = arD[jp + cj * 16 + m];
  }
#pragma unroll
  for (int cm = 0; cm < 4; cm++) {
#pragma unroll
    for (int r = 0; r < 4; r++) {
      int lrow = cm * 16 + q * 4 + r;
      int gm = m0 + lrow;
      float lp = 0.f, rp = 0.f;
#pragma unroll
      for (int cj = 0; cj < 4; cj++) {
        float v = acc[cm][cj][r];
        if (gm < M) emb1[(size_t)gm * 256 + jp + cj * 16 + m] = f2b(v);
        lp += v * al[cj]; rp += v * ar[cj];
      }
      lp += __shfl_xor(lp, 4); lp += __shfl_xor(lp, 8);
      rp += __shfl_xor(rp, 4); rp += __shfl_xor(rp, 8);
      if (m < 4) { lsum[wv][lrow][m] = lp; rsum[wv][lrow][m] = rp; }
    }
  }
  __syncthreads();
  {
    int row_ = tid >> 2, h = tid & 3;
    int gm = m0 + row_;
    if (gm < M) {
      float l = lsum[0][row_][h] + lsum[1][row_][h] + lsum[2][row_][h] + lsum[3][row_][h];
      float r = rsum[0][row_][h] + rsum[1][row_][h] + rsum[2][row_][h] + rsum[3][row_][h];
      hl1[(size_t)gm * 4 + h] = l;
      hr1[(size_t)gm * 4 + h] = r;
    }
  }
}

// ---------- L2 GEMM, register double-buffered like gemm1: emb2 | res(+bias) ----------
__global__ __launch_bounds__(256, 2) void gemm2_fused(
    const unsigned short* __restrict__ A, int M,
    const unsigned short* __restrict__ Bt,      // W2t [128][256]
    unsigned short* __restrict__ emb2, unsigned short* __restrict__ res,
    const void* __restrict__ bias, const int* __restrict__ dflag) {
  __shared__ unsigned short As[64 * 64];
  __shared__ unsigned short Bs[128 * 64];
  int isf32 = *dflag;
  const int tid = threadIdx.x;
  const int m0 = blockIdx.x * 64;
  const int wv = tid >> 6, lane = tid & 63;
  const int q = lane >> 4, m = lane & 15;
  const int jp = (wv & 1) * 64;
  const int mh = (wv >> 1) * 32;
  const int arow = tid >> 2, aqt = tid & 3;
  const int gr = m0 + arow;
  f32x4 acc[2][4] = {};
  int4 aR[2];
  int4 bR[4];
  aR[0] = aR[1] = (int4){0, 0, 0, 0};
  auto loadA = [&](int kc) {
    if (gr < M) {
      const unsigned short* ap = A + (size_t)gr * 256 + kc + aqt * 16;
      aR[0] = *(const int4*)ap;
      aR[1] = *(const int4*)(ap + 8);
    }
  };
  auto loadB = [&](int kc) {
#pragma unroll
    for (int i = 0; i < 4; i++) {
      int id = tid + i * 256;
      int brow = id >> 3, bg = id & 7;
      bR[i] = *(const int4*)(Bt + (size_t)brow * 256 + kc + bg * 8);
    }
  };
  loadA(0); loadB(0);
  for (int kc = 0; kc < 256; kc += 64) {
    {
      int g0 = (aqt * 2) ^ (arow & 7);
      int g1 = (aqt * 2 + 1) ^ (arow & 7);
      *(int4*)(As + arow * 64 + g0 * 8) = aR[0];
      *(int4*)(As + arow * 64 + g1 * 8) = aR[1];
#pragma unroll
      for (int i = 0; i < 4; i++) {
        int id = tid + i * 256;
        int brow = id >> 3, bg = id & 7;
        int pg = bg ^ (brow & 7);
        *(int4*)(Bs + brow * 64 + pg * 8) = bR[i];
      }
    }
    __syncthreads();
    if (kc < 192) { loadA(kc + 64); loadB(kc + 64); }
#pragma unroll
    for (int ks = 0; ks < 2; ks++) {
      int gk = ks * 4 + q;
      bf16x8 afr[2];
#pragma unroll
      for (int cm = 0; cm < 2; cm++) {
        int row = mh + cm * 16 + m;
        afr[cm] = *(const bf16x8*)(As + row * 64 + (gk ^ (row & 7)) * 8);
      }
#pragma unroll
      for (int cj = 0; cj < 4; cj++) {
        int jr = jp + cj * 16 + m;
        bf16x8 b = *(const bf16x8*)(Bs + jr * 64 + (gk ^ (jr & 7)) * 8);
#pragma unroll
        for (int cm = 0; cm < 2; cm++)
          acc[cm][cj] = __builtin_amdgcn_mfma_f32_16x16x32_bf16(afr[cm], b, acc[cm][cj], 0, 0, 0);
      }
    }
    __syncthreads();
  }
  float bv[4];
#pragma unroll
  for (int cj = 0; cj < 4; cj++)
    bv[cj] = (jp == 64) ? ldf(bias, cj * 16 + m, isf32) : 0.f;
#pragma unroll
  for (int cm = 0; cm < 2; cm++) {
#pragma unroll
    for (int r = 0; r < 4; r++) {
      int gm = m0 + mh + cm * 16 + q * 4 + r;
      if (gm < M) {
#pragma unroll
        for (int cj = 0; cj < 4; cj++) {
          float v = acc[cm][cj][r];
          int gj = cj * 16 + m;
          if (jp == 0) emb2[(size_t)gm * 64 + gj] = f2b(v);
          else res[(size_t)gm * 64 + gj] = f2b(v + bv[cj]);
        }
      }
    }
  }
}

// ---------- CSR by destination (scan3 eliminated: final ptr = ptrb[i]+bsum[i>>8]) ----------
__global__ void scan1_kernel(const int* __restrict__ cnt, int* __restrict__ ptrb,
                             int* __restrict__ bsum, int n) {
  __shared__ int wsum[4];
  int tid = threadIdx.x, lane = tid & 63, wid = tid >> 6;
  int i = blockIdx.x * 256 + tid;
  int v = (i < n) ? cnt[i] : 0;
  int x = v;
#pragma unroll
  for (int off = 1; off < 64; off <<= 1) {
    int y = __shfl_up(x, off);
    if (lane >= off) x += y;
  }
  if (lane == 63) wsum[wid] = x;
  __syncthreads();
  int woff = 0;
#pragma unroll
  for (int k = 0; k < 4; k++) woff += (k < wid) ? wsum[k] : 0;
  if (i < n) ptrb[i] = x - v + woff;
  if (tid == 255) bsum[blockIdx.x] = woff + x;
}

__global__ void scan2_kernel(int* __restrict__ bsum, int* __restrict__ ptrb,
                             int nb, int n) {
  __shared__ int wsum[4];
  int tid = threadIdx.x, lane = tid & 63, wid = tid >> 6;
  int v = (tid < nb) ? bsum[tid] : 0;
  int x = v;
#pragma unroll
  for (int off = 1; off < 64; off <<= 1) {
    int y = __shfl_up(x, off);
    if (lane >= off) x += y;
  }
  if (lane == 63) wsum[wid] = x;
  __syncthreads();
  int woff = 0;
#pragma unroll
  for (int k = 0; k < 4; k++) woff += (k < wid) ? wsum[k] : 0;
  if (tid < nb) bsum[tid] = x - v + woff;
  if (tid == 255) ptrb[n] = woff + x;
}

// ---------- layer-1 aggregation: 4 nodes per wave (16 lanes/node) ----------
// At its gather-BW floor (~3.2 TB/s across three structures) - hot loop untouched.
__global__ __launch_bounds__(256) void agg1_kernel(
    const int* __restrict__ ptrb, const int* __restrict__ bsumv,
    const int* __restrict__ srcc,
    const float* __restrict__ hl1, const float* __restrict__ hr1,
    const float* __restrict__ he1,
    const unsigned short* __restrict__ emb1, unsigned short* __restrict__ h1,
    const float* __restrict__ a2l, const float* __restrict__ a2r,
    float* __restrict__ hl2, float* __restrict__ hr2,
    int n0, int N_, int E_) {
  __shared__ float4 wds[4][64];
  __shared__ int sds[4][64];
  const int tid = threadIdx.x;
  const int wv = tid >> 6, lane = tid & 63;
  const int g = lane >> 4, ln = lane & 15;
  const int node = n0 + blockIdx.x * 16 + wv * 4 + g;
  const bool nv = node < N_;
  int p0 = 0, p1 = 0;
  if (nv) {
    p0 = ptrb[node] + bsumv[node >> 8];
    p1 = (node + 1 < N_) ? (ptrb[node + 1] + bsumv[(node + 1) >> 8]) : ptrb[N_];
    p0 = max(0, min(p0, E_)); p1 = max(p0, min(p1, E_));
  }
  float4 hrv = {0.f, 0.f, 0.f, 0.f};
  if (nv) hrv = *(const float4*)(hr1 + 4 * (size_t)node);
  float s0 = 0.f, s1 = 0.f, s2 = 0.f, s3 = 0.f;
  float acc[16];
#pragma unroll
  for (int k = 0; k < 16; k++) acc[k] = 0.f;
  const unsigned short* erow = emb1 + ln * 16;
  for (int pb = p0;; pb += 16) {
    if (!__any(pb < p1)) break;
    int mc = (pb < p1) ? min(p1 - pb, 16) : 0;
    float4 w = {0.f, 0.f, 0.f, 0.f};
    int src = 0;
    if (ln < mc) {
      int spk = srcc[pb + ln];
      if (spk >= 0) {
        int sr = spk & 0xFFFFF, t = spk >> 20;
        float4 a = *(const float4*)(hl1 + 4 * (size_t)sr);
        float4 ge = *(const float4*)(he1 + 4 * (size_t)t);
        w.x = __expf(lrelu(a.x + hrv.x + ge.x));
        w.y = __expf(lrelu(a.y + hrv.y + ge.y));
        w.z = __expf(lrelu(a.z + hrv.z + ge.z));
        w.w = __expf(lrelu(a.w + hrv.w + ge.w));
        src = sr;
      }
    }
    s0 += w.x; s1 += w.y; s2 += w.z; s3 += w.w;
    // per-wave LDS region; in-order wave execution keeps this coherent
    wds[wv][lane] = w;
    sds[wv][lane] = src;
    for (int j = 0; j < mc; j += 2) {
      bool v1 = (j + 1) < mc;
      float4 u0 = wds[wv][g * 16 + j];
      int r0 = sds[wv][g * 16 + j];
      const unsigned short* e0 = erow + (size_t)r0 * 256;
      int4 ra = *(const int4*)e0;
      int4 rb = *(const int4*)(e0 + 8);
      float4 u1; int4 rc, rd;
      if (v1) {
        u1 = wds[wv][g * 16 + j + 1];
        int r1 = sds[wv][g * 16 + j + 1];
        const unsigned short* e1 = erow + (size_t)r1 * 256;
        rc = *(const int4*)e1;
        rd = *(const int4*)(e1 + 8);
      }
      acc[0]  += u0.x * lo2f(ra.x); acc[1]  += u0.y * hi2f(ra.x);
      acc[2]  += u0.z * lo2f(ra.y); acc[3]  += u0.w * hi2f(ra.y);
      acc[4]  += u0.x * lo2f(ra.z); acc[5]  += u0.y * hi2f(ra.z);
      acc[6]  += u0.z * lo2f(ra.w); acc[7]  += u0.w * hi2f(ra.w);
      acc[8]  += u0.x * lo2f(rb.x); acc[9]  += u0.y * hi2f(rb.x);
      acc[10] += u0.z * lo2f(rb.y); acc[11] += u0.w * hi2f(rb.y);
      acc[12] += u0.x * lo2f(rb.z); acc[13] += u0.y * hi2f(rb.z);
      acc[14] += u0.z * lo2f(rb.w); acc[15] += u0.w * hi2f(rb.w);
      if (v1) {
        acc[0]  += u1.x * lo2f(rc.x); acc[1]  += u1.y * hi2f(rc.x);
        acc[2]  += u1.z * lo2f(rc.y); acc[3]  += u1.w * hi2f(rc.y);
        acc[4]  += u1.x * lo2f(rc.z); acc[5]  += u1.y * hi2f(rc.z);
        acc[6]  += u1.z * lo2f(rc.w); acc[7]  += u1.w * hi2f(rc.w);
        acc[8]  += u1.x * lo2f(rd.x); acc[9]  += u1.y * hi2f(rd.x);
        acc[10] += u1.z * lo2f(rd.y); acc[11] += u1.w * hi2f(rd.y);
        acc[12] += u1.x * lo2f(rd.z); acc[13] += u1.y * hi2f(rd.z);
        acc[14] += u1.z * lo2f(rd.w); acc[15] += u1.w * hi2f(rd.w);
      }
    }
  }
#pragma unroll
  for (int off = 1; off < 16; off <<= 1) {
    s0 += __shfl_xor(s0, off); s1 += __shfl_xor(s1, off);
    s2 += __shfl_xor(s2, off); s3 += __shfl_xor(s3, off);
  }
  float invs[4];
  invs[0] = s0 > 0.f ? 1.f / s0 : 0.f;
  invs[1] = s1 > 0.f ? 1.f / s1 : 0.f;
  invs[2] = s2 > 0.f ? 1.f / s2 : 0.f;
  invs[3] = s3 > 0.f ? 1.f / s3 : 0.f;
  float alv[16], arv[16];
#pragma unroll
  for (int q2 = 0; q2 < 4; q2++) {
    float4 t1 = *(const float4*)(a2l + ln * 16 + q2 * 4);
    float4 t2 = *(const float4*)(a2r + ln * 16 + q2 * 4);
    alv[q2 * 4 + 0] = t1.x; alv[q2 * 4 + 1] = t1.y;
    alv[q2 * 4 + 2] = t1.z; alv[q2 * 4 + 3] = t1.w;
    arv[q2 * 4 + 0] = t2.x; arv[q2 * 4 + 1] = t2.y;
    arv[q2 * 4 + 2] = t2.z; arv[q2 * 4 + 3] = t2.w;
  }
  float lp = 0.f, rp = 0.f;
  unsigned int ow[8];
#pragma unroll
  for (int k = 0; k < 16; k++) {
    float r = acc[k] * invs[k & 3];
    r = r > 0.f ? r : __expf(r) - 1.f;       // elu
    unsigned int bb = f2b(r);
    if ((k & 1) == 0) ow[k >> 1] = bb; else ow[k >> 1] |= bb << 16;
    lp += r * alv[k];
    rp += r * arv[k];
  }
  if (nv) {
    int4 va; va.x = ow[0]; va.y = ow[1]; va.z = ow[2]; va.w = ow[3];
    int4 vb; vb.x = ow[4]; vb.y = ow[5]; vb.z = ow[6]; vb.w = ow[7];
    *(int4*)(h1 + (size_t)node * 256 + ln * 16) = va;
    *(int4*)(h1 + (size_t)node * 256 + ln * 16 + 8) = vb;
  }
#pragma unroll
  for (int off = 1; off < 16; off <<= 1) {
    lp += __shfl_xor(lp, off); rp += __shfl_xor(rp, off);
  }
  if (nv && ln == 0) { hl2[node] = lp; hr2[node] = rp; }
}

// ---------- layer-2 aggregation: 4 nodes per wave (16 lanes/node), depth-1 prefetch ----------
__global__ __launch_bounds__(256) void agg2_kernel(
    const int* __restrict__ ptrb, const int* __restrict__ bsumv,
    const int* __restrict__ srcc,
    const float* __restrict__ hl2, const float* __restrict__ hr2,
    const float* __restrict__ he2,
    const unsigned short* __restrict__ emb2, const unsigned short* __restrict__ res,
    void* __restrict__ out, int N_, int E_, const int* __restrict__ dflag) {
  __shared__ int2 wsd[4][4][17];                 // padded: groups land on distinct banks
  const int isf32 = *dflag;
  const int tid = threadIdx.x;
  const int wv = tid >> 6, lane = tid & 63;
  const int g = lane >> 4, ln = lane & 15;
  const int node = blockIdx.x * 16 + wv * 4 + g;
  const bool nv = node < N_;
  int p0 = 0, p1 = 0;
  if (nv) {
    p0 = ptrb[node] + bsumv[node >> 8];
    p1 = (node + 1 < N_) ? (ptrb[node + 1] + bsumv[(node + 1) >> 8]) : ptrb[N_];
    p0 = max(0, min(p0, E_)); p1 = max(p0, min(p1, E_));
  }
  float hrv = nv ? hr2[node] : 0.f;
  float s = 0.f;
  float acc[4] = {0.f, 0.f, 0.f, 0.f};
  const unsigned short* erow = emb2 + ln * 4;
  for (int pb = p0;; pb += 16) {
    if (!__any(pb < p1)) break;
    int mc = (pb < p1) ? min(p1 - pb, 16) : 0;
    float w = 0.f; int src = 0;
    if (ln < mc) {
      int spk = srcc[pb + ln];
      if (spk >= 0) {
        int sr = spk & 0xFFFFF, t = spk >> 20;
        w = __expf(lrelu(hl2[sr] + hrv + he2[t]));
        src = sr;
      }
    }
    s += w;
    int2 pk; pk.x = __float_as_int(w); pk.y = src;
    wsd[wv][g][ln] = pk;
    // pipelined consume: issue loads for pair j+2 before FMAs of pair j
    int2 w0 = {0, 0}, w1 = {0, 0}; int2 pa = {0, 0}, pc = {0, 0};
    if (0 < mc) { w0 = wsd[wv][g][0]; pa = *(const int2*)(erow + (size_t)w0.y * 64); }
    if (1 < mc) { w1 = wsd[wv][g][1]; pc = *(const int2*)(erow + (size_t)w1.y * 64); }
    for (int j = 0; j < mc; j += 2) {
      int2 nw0 = {0, 0}, nw1 = {0, 0}, na = {0, 0}, nc = {0, 0};
      if (j + 2 < mc) { nw0 = wsd[wv][g][j + 2]; na = *(const int2*)(erow + (size_t)nw0.y * 64); }
      if (j + 3 < mc) { nw1 = wsd[wv][g][j + 3]; nc = *(const int2*)(erow + (size_t)nw1.y * 64); }
      float u0 = __int_as_float(w0.x);
      acc[0] += u0 * lo2f(pa.x); acc[1] += u0 * hi2f(pa.x);
      acc[2] += u0 * lo2f(pa.y); acc[3] += u0 * hi2f(pa.y);
      if (j + 1 < mc) {
        float u1 = __int_as_float(w1.x);
        acc[0] += u1 * lo2f(pc.x); acc[1] += u1 * hi2f(pc.x);
        acc[2] += u1 * lo2f(pc.y); acc[3] += u1 * hi2f(pc.y);
      }
      w0 = nw0; w1 = nw1; pa = na; pc = nc;
    }
  }
#pragma unroll
  for (int off = 1; off < 16; off <<= 1) s += __shfl_xor(s, off);
  float inv = s > 0.f ? 1.f / s : 0.f;
  if (nv) {
    ushort4 rv = *(const ushort4*)(res + (size_t)node * 64 + ln * 4);
    float o0 = acc[0] * inv + b2f(rv.x);
    float o1 = acc[1] * inv + b2f(rv.y);
    float o2 = acc[2] * inv + b2f(rv.z);
    float o3 = acc[3] * inv + b2f(rv.w);
    size_t oi = (size_t)node * 64 + ln * 4;
    if (isf32) {
      float4 ov = {o0, o1, o2, o3};
      *(float4*)((float*)out + oi) = ov;
    } else {
      ushort4 ov; ov.x = f2b(o0); ov.y = f2b(o1); ov.z = f2b(o2); ov.w = f2b(o3);
      *(ushort4*)((unsigned short*)out + oi) = ov;
    }
  }
}

extern "C" void kernel_launch(void* const* d_in, const int* in_sizes, int n_in,
                              void* d_out, int out_size, void* d_ws, size_t ws_size,
                              hipStream_t stream) {
  const int N = in_sizes[0] / IN_DIM;
  const int E = in_sizes[1];

  const void* h   = d_in[0];
  const int* row  = (const int*)d_in[1];
  const int* col  = (const int*)d_in[2];
  const int* ety  = (const int*)d_in[3];
  const void* ee1 = d_in[4];
  const void* W1  = d_in[5];
  const void* Wr1 = d_in[6];
  const void* al1 = d_in[7];
  const void* ar1 = d_in[8];
  const void* ae1 = d_in[9];
  const void* ee2 = d_in[10];
  const void* W2  = d_in[11];
  const void* Wr2 = d_in[12];
  const void* al2 = d_in[13];
  const void* ar2 = d_in[14];
  const void* ae2 = d_in[15];
  const void* rW2 = d_in[16];
  const void* rb2 = d_in[17];

  char* p = (char*)d_ws;
  auto take = [&](size_t b) { char* q = p; p += (b + 255) & ~(size_t)255; return q; };
  unsigned short* h1   = (unsigned short*)take((size_t)N * 256 * 2);   // 25.6 MB
  unsigned short* emb1 = (unsigned short*)take((size_t)N * 256 * 2);   // 25.6 MB (layer2 aliases)
  int* srcc = (int*)take((size_t)E * 4);
  int* ptrb = (int*)take((size_t)(N + 1) * 4);
  int* cnt  = (int*)take((size_t)N * 4);
  int* bsum = (int*)take(1024);
  float* hl1 = (float*)take((size_t)N * 4 * 4);
  float* hr1 = (float*)take((size_t)N * 4 * 4);
  float* hl2 = (float*)take((size_t)N * 4);
  float* hr2 = (float*)take((size_t)N * 4);
  unsigned short* W1t = (unsigned short*)take(256 * 256 * 2);
  unsigned short* W2t = (unsigned short*)take(128 * 256 * 2);
  float* a2l = (float*)take(256 * 4);
  float* a2r = (float*)take(256 * 4);
  float* alD = (float*)take(256 * 4);
  float* arD = (float*)take(256 * 4);
  float* he1 = (float*)take(NT * 4 * 4);
  float* he2 = (float*)take(NT * 4);
  int* dflag = (int*)take(256);
  unsigned short* emb2 = emb1;                     // aliases dead emb1 after agg1
  unsigned short* res  = emb1 + (size_t)N * 64;

  const size_t need = (size_t)(p - (char*)d_ws);
  if (need > ws_size) {
    hipMemsetAsync(d_out, 0, (size_t)out_size * 2, stream);
    return;
  }

  const int ECB = (E + 1023) / 1024;
  const int MB = (N + 63) / 64;
  const int SB = (N + 255) / 256;
  const int AB = (N + 15) / 16;

  hipMemsetAsync(cnt, 0, (size_t)N * 4, stream);
  // prep + self-detect + edge count (one dispatch)
  prep_all_kernel<<<454 + ECB, 256, 0, stream>>>(
      W1, W2, rW2, al1, ar1, al2, ar2, ee1, Wr1, ae1, ee2, Wr2, ae2,
      W1t, W2t, a2l, a2r, he1, he2, alD, arD,
      (const unsigned int*)h, col, cnt, E, N, dflag);

  // CSR scan
  scan1_kernel<<<SB, 256, 0, stream>>>(cnt, ptrb, bsum, N);
  scan2_kernel<<<1, 256, 0, stream>>>(bsum, ptrb, SB, N);

  // CSR fill (first ECB blocks) + layer-1 GEMM co-resident in one dispatch
  gemm1_fill<<<ECB + MB, 256, 0, stream>>>(
      h, N, W1t, emb1, alD, arD, hl1, hr1, dflag, ECB,
      col, row, ety, ptrb, bsum, cnt, srcc, E);

  // layer-1 aggregation
  agg1_kernel<<<AB, 256, 0, stream>>>(
      ptrb, bsum, srcc, hl1, hr1, he1, emb1, h1, a2l, a2r, hl2, hr2, 0, N, E);

  // layer 2
  gemm2_fused<<<MB, 256, 0, stream>>>(h1, N, W2t, emb2, res, rb2, dflag);
  agg2_kernel<<<AB, 256, 0, stream>>>(
      ptrb, bsum, srcc, hl2, hr2, he2, emb2, res, d_out, N, E, dflag);
}

// Round 9
// 259.679 us; speedup vs baseline: 1.2521x; 1.2521x over previous
//
#include <hip/hip_runtime.h>
#include <hip/hip_bf16.h>

typedef __bf16 bf16x8 __attribute__((ext_vector_type(8)));
typedef float f32x4 __attribute__((ext_vector_type(4)));

#define IN_DIM 256
#define NT 8

__device__ __forceinline__ float b2f(unsigned short u) {
  union { unsigned int i; float f; } x; x.i = ((unsigned int)u) << 16; return x.f;
}
__device__ __forceinline__ float lo2f(unsigned int w) {
  union { unsigned int i; float f; } x; x.i = w << 16; return x.f;
}
__device__ __forceinline__ float hi2f(unsigned int w) {
  union { unsigned int i; float f; } x; x.i = w & 0xFFFF0000u; return x.f;
}
__device__ __forceinline__ unsigned short f2b(float f) {
  union { float f; unsigned int i; } u; u.f = f;
  unsigned int r = u.i + 0x7FFF + ((u.i >> 16) & 1);
  return (unsigned short)(r >> 16);
}
__device__ __forceinline__ unsigned int f2b2(float lo, float hi) {
  return (unsigned int)f2b(lo) | ((unsigned int)f2b(hi) << 16);
}
__device__ __forceinline__ float lrelu(float x) { return x >= 0.f ? x : 0.2f * x; }
__device__ __forceinline__ float ldf(const void* p, size_t i, int isf32) {
  return isf32 ? ((const float*)p)[i] : b2f(((const unsigned short*)p)[i]);
}

// ---------- fused prep: [0,384) W-transpose; [384,448) fold a2; [448,454) he/aD;
// [454, 454+ECB) edge count (4 edges/thread). Each prep block self-detects dtype. ----------
__global__ void prep_all_kernel(const void* __restrict__ W1, const void* __restrict__ W2,
                                const void* __restrict__ rW2,
                                const void* __restrict__ al1, const void* __restrict__ ar1,
                                const void* __restrict__ al2, const void* __restrict__ ar2,
                                const void* __restrict__ ee1, const void* __restrict__ Wr1,
                                const void* __restrict__ ae1,
                                const void* __restrict__ ee2, const void* __restrict__ Wr2,
                                const void* __restrict__ ae2,
                                unsigned short* __restrict__ W1t,
                                unsigned short* __restrict__ W2t,
                                float* __restrict__ a2l, float* __restrict__ a2r,
                                float* __restrict__ he1, float* __restrict__ he2,
                                float* __restrict__ alD, float* __restrict__ arD,
                                const unsigned int* __restrict__ hw,
                                const int* __restrict__ col, int* __restrict__ cnt,
                                int E_, int N_, int* __restrict__ dflag) {
  int b = blockIdx.x, tid = threadIdx.x;
  if (b >= 454) {
    // edge-count role (CSR histogram), 4 edges/thread
    int base = (b - 454) * 1024 + tid;
#pragma unroll
    for (int k = 0; k < 4; k++) {
      int e = base + k * 256;
      if (e < E_) {
        int c = col[e];
        if ((unsigned)c < (unsigned)N_) atomicAdd(&cnt[c], 1);
      }
    }
    return;
  }
  // self-detect dtype of h (wave 0 only, broadcast via LDS)
  __shared__ int sflag;
  {
    int bad = 0;
    if (tid < 64) {
      for (int i = 0; i < 4; i++) {
        unsigned int w = hw[tid * 4 + i];
        unsigned int ex = (w & 0x7FFFu) >> 7;
        if (ex >= 0xC0u) bad++;
      }
#pragma unroll
      for (int off = 32; off; off >>= 1) bad += __shfl_xor(bad, off);
      if (tid == 0) sflag = (bad > 8) ? 1 : 0;
    }
    __syncthreads();
  }
  const int isf32 = sflag;
  if (b == 0 && tid == 0) *dflag = isf32;
  if (b < 384) {
    int j = b, k = tid;
    if (j < 256) {
      int src = (j & 3) * 64 + (j >> 2);          // h*64+d
      W1t[j * 256 + k] = f2b(ldf(W1, (size_t)k * 256 + src, isf32));
    } else {
      int o = j - 256;
      float v = (o < 64) ? ldf(W2, (size_t)k * 64 + o, isf32)
                         : ldf(rW2, (size_t)k * 64 + (o - 64), isf32);
      W2t[o * 256 + k] = f2b(v);
    }
  } else if (b < 448) {
    int k = (b - 384) * 4 + (tid >> 6), d = tid & 63;
    float w2 = ldf(W2, (size_t)k * 64 + d, isf32);
    float l2 = w2 * ldf(al2, d, isf32);
    float r2 = w2 * ldf(ar2, d, isf32);
#pragma unroll
    for (int off = 32; off; off >>= 1) { l2 += __shfl_xor(l2, off); r2 += __shfl_xor(r2, off); }
    if (d == 0) { a2l[k] = l2; a2r[k] = r2; }
  } else {
    int bid = b - 448;
    int t = tid >> 5, d = tid & 31;
    if (bid < 4) {
      int h = bid;
      float s = 0.f;
#pragma unroll
      for (int e = 0; e < 32; e++)
        s += ldf(ee1, t * 32 + e, isf32) * ldf(Wr1, (size_t)(t * 32 + e) * 128 + h * 32 + d, isf32);
      float v = s * ldf(ae1, h * 32 + d, isf32);
#pragma unroll
      for (int off = 16; off; off >>= 1) v += __shfl_xor(v, off);
      if (d == 0) he1[t * 4 + h] = v;
    } else if (bid == 4) {
      float s = 0.f;
#pragma unroll
      for (int e = 0; e < 32; e++)
        s += ldf(ee2, t * 32 + e, isf32) * ldf(Wr2, (size_t)(t * 32 + e) * 32 + d, isf32);
      float v = s * ldf(ae2, d, isf32);
#pragma unroll
      for (int off = 16; off; off >>= 1) v += __shfl_xor(v, off);
      if (d == 0) he2[t] = v;
    } else {
      int j = tid;                       // D-major a vectors
      alD[j] = ldf(al1, (j & 3) * 64 + (j >> 2), isf32);
      arD[j] = ldf(ar1, (j & 3) * 64 + (j >> 2), isf32);
    }
  }
}

// ---------- L1 GEMM + CSR-fill (fill role FIRST, blocks [0,FillBlocks)).
// Register double-buffer with NAMED variables only (round-8's array+pointer-cast
// version spilled to scratch: VGPR=80, WRITE 214MB). Loads for chunk k+1 issue
// right after the stage barrier, drain at the next stage; MFMA covers HBM latency.
// Same 2 barriers/chunk, 48KB LDS, 2 blocks/CU as round-6 (49us baseline). ----------
#define G1_LOADB(kcv) do {                                                              \
    int id0_ = tid;        b0 = *(const int4*)(Bt + (size_t)(id0_ >> 3) * 256 + (kcv) + (id0_ & 7) * 8); \
    int id1_ = tid + 256;  b1 = *(const int4*)(Bt + (size_t)(id1_ >> 3) * 256 + (kcv) + (id1_ & 7) * 8); \
    int id2_ = tid + 512;  b2 = *(const int4*)(Bt + (size_t)(id2_ >> 3) * 256 + (kcv) + (id2_ & 7) * 8); \
    int id3_ = tid + 768;  b3 = *(const int4*)(Bt + (size_t)(id3_ >> 3) * 256 + (kcv) + (id3_ & 7) * 8); \
    int id4_ = tid + 1024; b4 = *(const int4*)(Bt + (size_t)(id4_ >> 3) * 256 + (kcv) + (id4_ & 7) * 8); \
    int id5_ = tid + 1280; b5 = *(const int4*)(Bt + (size_t)(id5_ >> 3) * 256 + (kcv) + (id5_ & 7) * 8); \
    int id6_ = tid + 1536; b6 = *(const int4*)(Bt + (size_t)(id6_ >> 3) * 256 + (kcv) + (id6_ & 7) * 8); \
    int id7_ = tid + 1792; b7 = *(const int4*)(Bt + (size_t)(id7_ >> 3) * 256 + (kcv) + (id7_ & 7) * 8); \
  } while (0)

#define G1_STOREB(iv, src) do {                                                         \
    int id_ = tid + (iv) * 256; int brow_ = id_ >> 3;                                   \
    int pg_ = (id_ & 7) ^ (brow_ & 7);                                                  \
    *(int4*)(Bs + brow_ * 64 + pg_ * 8) = (src);                                        \
  } while (0)

#define G1_LOADA(kcv) do {                                                              \
    if (gr < M) {                                                                       \
      if (isf32) {                                                                      \
        const float* ap_ = (const float*)A + (size_t)gr * 256 + (kcv) + aqt * 16;       \
        af0 = *(const float4*)ap_;        af1 = *(const float4*)(ap_ + 4);              \
        af2 = *(const float4*)(ap_ + 8);  af3 = *(const float4*)(ap_ + 12);             \
      } else {                                                                          \
        const unsigned short* ap_ = (const unsigned short*)A + (size_t)gr * 256 + (kcv) + aqt * 16; \
        ab0 = *(const int4*)ap_;  ab1 = *(const int4*)(ap_ + 8);                        \
      }                                                                                 \
    }                                                                                   \
  } while (0)

__global__ __launch_bounds__(256, 2) void gemm1_fill(
    const void* __restrict__ A, int M,
    const unsigned short* __restrict__ Bt,      // W1t [256][256]
    unsigned short* __restrict__ emb1,
    const float* __restrict__ alD, const float* __restrict__ arD,
    float* __restrict__ hl1, float* __restrict__ hr1,
    const int* __restrict__ dflag, int FillBlocks,
    const int* __restrict__ col, const int* __restrict__ row,
    const int* __restrict__ ety, const int* __restrict__ ptrb,
    const int* __restrict__ bsum, int* __restrict__ cnt,
    int* __restrict__ srcc, int E_) {
  __shared__ unsigned short As[64 * 64];        // 8 KB
  __shared__ unsigned short Bs[256 * 64];       // 32 KB
  __shared__ float lsum[4][64][4];              // 4 KB
  __shared__ float rsum[4][64][4];              // 4 KB
  if (blockIdx.x < FillBlocks) {
    int base = blockIdx.x * 1024 + threadIdx.x;
#pragma unroll
    for (int k = 0; k < 4; k++) {
      int e = base + k * 256;
      if (e < E_) {
        int c = col[e];
        if ((unsigned)c < (unsigned)M) {
          int pos = atomicSub(&cnt[c], 1) - 1;
          long long slot = (long long)(ptrb[c] + bsum[c >> 8]) + pos;
          if (slot >= 0 && slot < E_) {
            int sr = row[e], t = ety[e];
            srcc[slot] = ((unsigned)sr < (unsigned)M && (unsigned)t < (unsigned)NT)
                             ? (sr | (t << 20)) : -1;
          }
        }
      }
    }
    return;
  }
  const int isf32 = *dflag;
  const int tid = threadIdx.x;
  const int m0 = (blockIdx.x - FillBlocks) * 64;
  const int wv = tid >> 6, lane = tid & 63;
  const int q = lane >> 4, m = lane & 15;
  const int jp = wv * 64;
  const int arow = tid >> 2, aqt = tid & 3;
  const int gr = m0 + arow;
  f32x4 acc[4][4] = {};
  float4 af0 = {0.f, 0.f, 0.f, 0.f}, af1 = af0, af2 = af0, af3 = af0;
  int4 ab0 = {0, 0, 0, 0}, ab1 = ab0;
  int4 b0, b1, b2, b3, b4, b5, b6, b7;

  G1_LOADA(0);
  G1_LOADB(0);
  for (int kc = 0; kc < 256; kc += 64) {
    {   // stage regs -> LDS (f32->bf16 convert via member access; no array addressing)
      int4 w0, w1;
      if (isf32) {
        w0.x = (int)f2b2(af0.x, af0.y); w0.y = (int)f2b2(af0.z, af0.w);
        w0.z = (int)f2b2(af1.x, af1.y); w0.w = (int)f2b2(af1.z, af1.w);
        w1.x = (int)f2b2(af2.x, af2.y); w1.y = (int)f2b2(af2.z, af2.w);
        w1.z = (int)f2b2(af3.x, af3.y); w1.w = (int)f2b2(af3.z, af3.w);
      } else {
        w0 = ab0; w1 = ab1;
      }
      int g0 = (aqt * 2) ^ (arow & 7);
      int g1 = (aqt * 2 + 1) ^ (arow & 7);
      *(int4*)(As + arow * 64 + g0 * 8) = w0;
      *(int4*)(As + arow * 64 + g1 * 8) = w1;
      G1_STOREB(0, b0); G1_STOREB(1, b1); G1_STOREB(2, b2); G1_STOREB(3, b3);
      G1_STOREB(4, b4); G1_STOREB(5, b5); G1_STOREB(6, b6); G1_STOREB(7, b7);
    }
    __syncthreads();
    if (kc < 192) { G1_LOADA(kc + 64); G1_LOADB(kc + 64); }  // in flight across MFMA
#pragma unroll
    for (int ks = 0; ks < 2; ks++) {
      int gk = ks * 4 + q;
      bf16x8 afr[4];
#pragma unroll
      for (int cm = 0; cm < 4; cm++) {
        int row_ = cm * 16 + m;
        afr[cm] = *(const bf16x8*)(As + row_ * 64 + (gk ^ (row_ & 7)) * 8);
      }
#pragma unroll
      for (int cj = 0; cj < 4; cj++) {
        int jr = jp + cj * 16 + m;
        bf16x8 b = *(const bf16x8*)(Bs + jr * 64 + (gk ^ (jr & 7)) * 8);
#pragma unroll
        for (int cm = 0; cm < 4; cm++)
          acc[cm][cj] = __builtin_amdgcn_mfma_f32_16x16x32_bf16(afr[cm], b, acc[cm][cj], 0, 0, 0);
      }
    }
    __syncthreads();
  }
  float al[4], ar[4];
#pragma unroll
  for (int cj = 0; cj < 4; cj++) {
    al[cj] = alD[jp + cj * 16 + m];
    ar[cj] = arD[jp + cj * 16 + m];
  }
#pragma unroll
  for (int cm = 0; cm < 4; cm++) {
#pragma unroll
    for (int r = 0; r < 4; r++) {
      int lrow = cm * 16 + q * 4 + r;
      int gm = m0 + lrow;
      float lp = 0.f, rp = 0.f;
#pragma unroll
      for (int cj = 0; cj < 4; cj++) {
        float v = acc[cm][cj][r];
        if (gm < M) emb1[(size_t)gm * 256 + jp + cj * 16 + m] = f2b(v);
        lp += v * al[cj]; rp += v * ar[cj];
      }
      lp += __shfl_xor(lp, 4); lp += __shfl_xor(lp, 8);
      rp += __shfl_xor(rp, 4); rp += __shfl_xor(rp, 8);
      if (m < 4) { lsum[wv][lrow][m] = lp; rsum[wv][lrow][m] = rp; }
    }
  }
  __syncthreads();
  {
    int row_ = tid >> 2, h = tid & 3;
    int gm = m0 + row_;
    if (gm < M) {
      float l = lsum[0][row_][h] + lsum[1][row_][h] + lsum[2][row_][h] + lsum[3][row_][h];
      float r = rsum[0][row_][h] + rsum[1][row_][h] + rsum[2][row_][h] + rsum[3][row_][h];
      hl1[(size_t)gm * 4 + h] = l;
      hr1[(size_t)gm * 4 + h] = r;
    }
  }
}

// ---------- L2 GEMM, named-register double-buffer: emb2 | res(+bias) ----------
#define G2_LOADB(kcv) do {                                                              \
    int id0_ = tid;        b0 = *(const int4*)(Bt + (size_t)(id0_ >> 3) * 256 + (kcv) + (id0_ & 7) * 8); \
    int id1_ = tid + 256;  b1 = *(const int4*)(Bt + (size_t)(id1_ >> 3) * 256 + (kcv) + (id1_ & 7) * 8); \
    int id2_ = tid + 512;  b2 = *(const int4*)(Bt + (size_t)(id2_ >> 3) * 256 + (kcv) + (id2_ & 7) * 8); \
    int id3_ = tid + 768;  b3 = *(const int4*)(Bt + (size_t)(id3_ >> 3) * 256 + (kcv) + (id3_ & 7) * 8); \
  } while (0)

__global__ __launch_bounds__(256, 2) void gemm2_fused(
    const unsigned short* __restrict__ A, int M,
    const unsigned short* __restrict__ Bt,      // W2t [128][256]
    unsigned short* __restrict__ emb2, unsigned short* __restrict__ res,
    const void* __restrict__ bias, const int* __restrict__ dflag) {
  __shared__ unsigned short As[64 * 64];
  __shared__ unsigned short Bs[128 * 64];
  int isf32 = *dflag;
  const int tid = threadIdx.x;
  const int m0 = blockIdx.x * 64;
  const int wv = tid >> 6, lane = tid & 63;
  const int q = lane >> 4, m = lane & 15;
  const int jp = (wv & 1) * 64;
  const int mh = (wv >> 1) * 32;
  const int arow = tid >> 2, aqt = tid & 3;
  const int gr = m0 + arow;
  f32x4 acc[2][4] = {};
  int4 ab0 = {0, 0, 0, 0}, ab1 = ab0;
  int4 b0, b1, b2, b3;
#define G2_LOADA(kcv) do {                                                              \
    if (gr < M) {                                                                       \
      const unsigned short* ap_ = A + (size_t)gr * 256 + (kcv) + aqt * 16;              \
      ab0 = *(const int4*)ap_; ab1 = *(const int4*)(ap_ + 8);                           \
    }                                                                                   \
  } while (0)
  G2_LOADA(0);
  G2_LOADB(0);
  for (int kc = 0; kc < 256; kc += 64) {
    {
      int g0 = (aqt * 2) ^ (arow & 7);
      int g1 = (aqt * 2 + 1) ^ (arow & 7);
      *(int4*)(As + arow * 64 + g0 * 8) = ab0;
      *(int4*)(As + arow * 64 + g1 * 8) = ab1;
      G1_STOREB(0, b0); G1_STOREB(1, b1); G1_STOREB(2, b2); G1_STOREB(3, b3);
    }
    __syncthreads();
    if (kc < 192) { G2_LOADA(kc + 64); G2_LOADB(kc + 64); }
#pragma unroll
    for (int ks = 0; ks < 2; ks++) {
      int gk = ks * 4 + q;
      bf16x8 afr[2];
#pragma unroll
      for (int cm = 0; cm < 2; cm++) {
        int row = mh + cm * 16 + m;
        afr[cm] = *(const bf16x8*)(As + row * 64 + (gk ^ (row & 7)) * 8);
      }
#pragma unroll
      for (int cj = 0; cj < 4; cj++) {
        int jr = jp + cj * 16 + m;
        bf16x8 b = *(const bf16x8*)(Bs + jr * 64 + (gk ^ (jr & 7)) * 8);
#pragma unroll
        for (int cm = 0; cm < 2; cm++)
          acc[cm][cj] = __builtin_amdgcn_mfma_f32_16x16x32_bf16(afr[cm], b, acc[cm][cj], 0, 0, 0);
      }
    }
    __syncthreads();
  }
  float bv[4];
#pragma unroll
  for (int cj = 0; cj < 4; cj++)
    bv[cj] = (jp == 64) ? ldf(bias, cj * 16 + m, isf32) : 0.f;
#pragma unroll
  for (int cm = 0; cm < 2; cm++) {
#pragma unroll
    for (int r = 0; r < 4; r++) {
      int gm = m0 + mh + cm * 16 + q * 4 + r;
      if (gm < M) {
#pragma unroll
        for (int cj = 0; cj < 4; cj++) {
          float v = acc[cm][cj][r];
          int gj = cj * 16 + m;
          if (jp == 0) emb2[(size_t)gm * 64 + gj] = f2b(v);
          else res[(size_t)gm * 64 + gj] = f2b(v + bv[cj]);
        }
      }
    }
  }
}

// ---------- CSR by destination (scan3 eliminated: final ptr = ptrb[i]+bsum[i>>8]) ----------
__global__ void scan1_kernel(const int* __restrict__ cnt, int* __restrict__ ptrb,
                             int* __restrict__ bsum, int n) {
  __shared__ int wsum[4];
  int tid = threadIdx.x, lane = tid & 63, wid = tid >> 6;
  int i = blockIdx.x * 256 + tid;
  int v = (i < n) ? cnt[i] : 0;
  int x = v;
#pragma unroll
  for (int off = 1; off < 64; off <<= 1) {
    int y = __shfl_up(x, off);
    if (lane >= off) x += y;
  }
  if (lane == 63) wsum[wid] = x;
  __syncthreads();
  int woff = 0;
#pragma unroll
  for (int k = 0; k < 4; k++) woff += (k < wid) ? wsum[k] : 0;
  if (i < n) ptrb[i] = x - v + woff;
  if (tid == 255) bsum[blockIdx.x] = woff + x;
}

__global__ void scan2_kernel(int* __restrict__ bsum, int* __restrict__ ptrb,
                             int nb, int n) {
  __shared__ int wsum[4];
  int tid = threadIdx.x, lane = tid & 63, wid = tid >> 6;
  int v = (tid < nb) ? bsum[tid] : 0;
  int x = v;
#pragma unroll
  for (int off = 1; off < 64; off <<= 1) {
    int y = __shfl_up(x, off);
    if (lane >= off) x += y;
  }
  if (lane == 63) wsum[wid] = x;
  __syncthreads();
  int woff = 0;
#pragma unroll
  for (int k = 0; k < 4; k++) woff += (k < wid) ? wsum[k] : 0;
  if (tid < nb) bsum[tid] = x - v + woff;
  if (tid == 255) ptrb[n] = woff + x;
}

// ---------- layer-1 aggregation: 4 nodes per wave (16 lanes/node) ----------
// At its gather-BW floor (~3.2 TB/s across three structures) - hot loop untouched.
__global__ __launch_bounds__(256) void agg1_kernel(
    const int* __restrict__ ptrb, const int* __restrict__ bsumv,
    const int* __restrict__ srcc,
    const float* __restrict__ hl1, const float* __restrict__ hr1,
    const float* __restrict__ he1,
    const unsigned short* __restrict__ emb1, unsigned short* __restrict__ h1,
    const float* __restrict__ a2l, const float* __restrict__ a2r,
    float* __restrict__ hl2, float* __restrict__ hr2,
    int n0, int N_, int E_) {
  __shared__ float4 wds[4][64];
  __shared__ int sds[4][64];
  const int tid = threadIdx.x;
  const int wv = tid >> 6, lane = tid & 63;
  const int g = lane >> 4, ln = lane & 15;
  const int node = n0 + blockIdx.x * 16 + wv * 4 + g;
  const bool nv = node < N_;
  int p0 = 0, p1 = 0;
  if (nv) {
    p0 = ptrb[node] + bsumv[node >> 8];
    p1 = (node + 1 < N_) ? (ptrb[node + 1] + bsumv[(node + 1) >> 8]) : ptrb[N_];
    p0 = max(0, min(p0, E_)); p1 = max(p0, min(p1, E_));
  }
  float4 hrv = {0.f, 0.f, 0.f, 0.f};
  if (nv) hrv = *(const float4*)(hr1 + 4 * (size_t)node);
  float s0 = 0.f, s1 = 0.f, s2 = 0.f, s3 = 0.f;
  float acc[16];
#pragma unroll
  for (int k = 0; k < 16; k++) acc[k] = 0.f;
  const unsigned short* erow = emb1 + ln * 16;
  for (int pb = p0;; pb += 16) {
    if (!__any(pb < p1)) break;
    int mc = (pb < p1) ? min(p1 - pb, 16) : 0;
    float4 w = {0.f, 0.f, 0.f, 0.f};
    int src = 0;
    if (ln < mc) {
      int spk = srcc[pb + ln];
      if (spk >= 0) {
        int sr = spk & 0xFFFFF, t = spk >> 20;
        float4 a = *(const float4*)(hl1 + 4 * (size_t)sr);
        float4 ge = *(const float4*)(he1 + 4 * (size_t)t);
        w.x = __expf(lrelu(a.x + hrv.x + ge.x));
        w.y = __expf(lrelu(a.y + hrv.y + ge.y));
        w.z = __expf(lrelu(a.z + hrv.z + ge.z));
        w.w = __expf(lrelu(a.w + hrv.w + ge.w));
        src = sr;
      }
    }
    s0 += w.x; s1 += w.y; s2 += w.z; s3 += w.w;
    // per-wave LDS region; in-order wave execution keeps this coherent
    wds[wv][lane] = w;
    sds[wv][lane] = src;
    for (int j = 0; j < mc; j += 2) {
      bool v1 = (j + 1) < mc;
      float4 u0 = wds[wv][g * 16 + j];
      int r0 = sds[wv][g * 16 + j];
      const unsigned short* e0 = erow + (size_t)r0 * 256;
      int4 ra = *(const int4*)e0;
      int4 rb = *(const int4*)(e0 + 8);
      float4 u1; int4 rc, rd;
      if (v1) {
        u1 = wds[wv][g * 16 + j + 1];
        int r1 = sds[wv][g * 16 + j + 1];
        const unsigned short* e1 = erow + (size_t)r1 * 256;
        rc = *(const int4*)e1;
        rd = *(const int4*)(e1 + 8);
      }
      acc[0]  += u0.x * lo2f(ra.x); acc[1]  += u0.y * hi2f(ra.x);
      acc[2]  += u0.z * lo2f(ra.y); acc[3]  += u0.w * hi2f(ra.y);
      acc[4]  += u0.x * lo2f(ra.z); acc[5]  += u0.y * hi2f(ra.z);
      acc[6]  += u0.z * lo2f(ra.w); acc[7]  += u0.w * hi2f(ra.w);
      acc[8]  += u0.x * lo2f(rb.x); acc[9]  += u0.y * hi2f(rb.x);
      acc[10] += u0.z * lo2f(rb.y); acc[11] += u0.w * hi2f(rb.y);
      acc[12] += u0.x * lo2f(rb.z); acc[13] += u0.y * hi2f(rb.z);
      acc[14] += u0.z * lo2f(rb.w); acc[15] += u0.w * hi2f(rb.w);
      if (v1) {
        acc[0]  += u1.x * lo2f(rc.x); acc[1]  += u1.y * hi2f(rc.x);
        acc[2]  += u1.z * lo2f(rc.y); acc[3]  += u1.w * hi2f(rc.y);
        acc[4]  += u1.x * lo2f(rc.z); acc[5]  += u1.y * hi2f(rc.z);
        acc[6]  += u1.z * lo2f(rc.w); acc[7]  += u1.w * hi2f(rc.w);
        acc[8]  += u1.x * lo2f(rd.x); acc[9]  += u1.y * hi2f(rd.x);
        acc[10] += u1.z * lo2f(rd.y); acc[11] += u1.w * hi2f(rd.y);
        acc[12] += u1.x * lo2f(rd.z); acc[13] += u1.y * hi2f(rd.z);
        acc[14] += u1.z * lo2f(rd.w); acc[15] += u1.w * hi2f(rd.w);
      }
    }
  }
#pragma unroll
  for (int off = 1; off < 16; off <<= 1) {
    s0 += __shfl_xor(s0, off); s1 += __shfl_xor(s1, off);
    s2 += __shfl_xor(s2, off); s3 += __shfl_xor(s3, off);
  }
  float invs[4];
  invs[0] = s0 > 0.f ? 1.f / s0 : 0.f;
  invs[1] = s1 > 0.f ? 1.f / s1 : 0.f;
  invs[2] = s2 > 0.f ? 1.f / s2 : 0.f;
  invs[3] = s3 > 0.f ? 1.f / s3 : 0.f;
  float alv[16], arv[16];
#pragma unroll
  for (int q2 = 0; q2 < 4; q2++) {
    float4 t1 = *(const float4*)(a2l + ln * 16 + q2 * 4);
    float4 t2 = *(const float4*)(a2r + ln * 16 + q2 * 4);
    alv[q2 * 4 + 0] = t1.x; alv[q2 * 4 + 1] = t1.y;
    alv[q2 * 4 + 2] = t1.z; alv[q2 * 4 + 3] = t1.w;
    arv[q2 * 4 + 0] = t2.x; arv[q2 * 4 + 1] = t2.y;
    arv[q2 * 4 + 2] = t2.z; arv[q2 * 4 + 3] = t2.w;
  }
  float lp = 0.f, rp = 0.f;
  unsigned int ow[8];
#pragma unroll
  for (int k = 0; k < 16; k++) {
    float r = acc[k] * invs[k & 3];
    r = r > 0.f ? r : __expf(r) - 1.f;       // elu
    unsigned int bb = f2b(r);
    if ((k & 1) == 0) ow[k >> 1] = bb; else ow[k >> 1] |= bb << 16;
    lp += r * alv[k];
    rp += r * arv[k];
  }
  if (nv) {
    int4 va; va.x = ow[0]; va.y = ow[1]; va.z = ow[2]; va.w = ow[3];
    int4 vb; vb.x = ow[4]; vb.y = ow[5]; vb.z = ow[6]; vb.w = ow[7];
    *(int4*)(h1 + (size_t)node * 256 + ln * 16) = va;
    *(int4*)(h1 + (size_t)node * 256 + ln * 16 + 8) = vb;
  }
#pragma unroll
  for (int off = 1; off < 16; off <<= 1) {
    lp += __shfl_xor(lp, off); rp += __shfl_xor(rp, off);
  }
  if (nv && ln == 0) { hl2[node] = lp; hr2[node] = rp; }
}

// ---------- layer-2 aggregation: 4 nodes per wave (16 lanes/node), depth-1 prefetch ----------
__global__ __launch_bounds__(256) void agg2_kernel(
    const int* __restrict__ ptrb, const int* __restrict__ bsumv,
    const int* __restrict__ srcc,
    const float* __restrict__ hl2, const float* __restrict__ hr2,
    const float* __restrict__ he2,
    const unsigned short* __restrict__ emb2, const unsigned short* __restrict__ res,
    void* __restrict__ out, int N_, int E_, const int* __restrict__ dflag) {
  __shared__ int2 wsd[4][4][17];                 // padded: groups land on distinct banks
  const int isf32 = *dflag;
  const int tid = threadIdx.x;
  const int wv = tid >> 6, lane = tid & 63;
  const int g = lane >> 4, ln = lane & 15;
  const int node = blockIdx.x * 16 + wv * 4 + g;
  const bool nv = node < N_;
  int p0 = 0, p1 = 0;
  if (nv) {
    p0 = ptrb[node] + bsumv[node >> 8];
    p1 = (node + 1 < N_) ? (ptrb[node + 1] + bsumv[(node + 1) >> 8]) : ptrb[N_];
    p0 = max(0, min(p0, E_)); p1 = max(p0, min(p1, E_));
  }
  float hrv = nv ? hr2[node] : 0.f;
  float s = 0.f;
  float acc[4] = {0.f, 0.f, 0.f, 0.f};
  const unsigned short* erow = emb2 + ln * 4;
  for (int pb = p0;; pb += 16) {
    if (!__any(pb < p1)) break;
    int mc = (pb < p1) ? min(p1 - pb, 16) : 0;
    float w = 0.f; int src = 0;
    if (ln < mc) {
      int spk = srcc[pb + ln];
      if (spk >= 0) {
        int sr = spk & 0xFFFFF, t = spk >> 20;
        w = __expf(lrelu(hl2[sr] + hrv + he2[t]));
        src = sr;
      }
    }
    s += w;
    int2 pk; pk.x = __float_as_int(w); pk.y = src;
    wsd[wv][g][ln] = pk;
    // pipelined consume: issue loads for pair j+2 before FMAs of pair j
    int2 w0 = {0, 0}, w1 = {0, 0}; int2 pa = {0, 0}, pc = {0, 0};
    if (0 < mc) { w0 = wsd[wv][g][0]; pa = *(const int2*)(erow + (size_t)w0.y * 64); }
    if (1 < mc) { w1 = wsd[wv][g][1]; pc = *(const int2*)(erow + (size_t)w1.y * 64); }
    for (int j = 0; j < mc; j += 2) {
      int2 nw0 = {0, 0}, nw1 = {0, 0}, na = {0, 0}, nc = {0, 0};
      if (j + 2 < mc) { nw0 = wsd[wv][g][j + 2]; na = *(const int2*)(erow + (size_t)nw0.y * 64); }
      if (j + 3 < mc) { nw1 = wsd[wv][g][j + 3]; nc = *(const int2*)(erow + (size_t)nw1.y * 64); }
      float u0 = __int_as_float(w0.x);
      acc[0] += u0 * lo2f(pa.x); acc[1] += u0 * hi2f(pa.x);
      acc[2] += u0 * lo2f(pa.y); acc[3] += u0 * hi2f(pa.y);
      if (j + 1 < mc) {
        float u1 = __int_as_float(w1.x);
        acc[0] += u1 * lo2f(pc.x); acc[1] += u1 * hi2f(pc.x);
        acc[2] += u1 * lo2f(pc.y); acc[3] += u1 * hi2f(pc.y);
      }
      w0 = nw0; w1 = nw1; pa = na; pc = nc;
    }
  }
#pragma unroll
  for (int off = 1; off < 16; off <<= 1) s += __shfl_xor(s, off);
  float inv = s > 0.f ? 1.f / s : 0.f;
  if (nv) {
    ushort4 rv = *(const ushort4*)(res + (size_t)node * 64 + ln * 4);
    float o0 = acc[0] * inv + b2f(rv.x);
    float o1 = acc[1] * inv + b2f(rv.y);
    float o2 = acc[2] * inv + b2f(rv.z);
    float o3 = acc[3] * inv + b2f(rv.w);
    size_t oi = (size_t)node * 64 + ln * 4;
    if (isf32) {
      float4 ov = {o0, o1, o2, o3};
      *(float4*)((float*)out + oi) = ov;
    } else {
      ushort4 ov; ov.x = f2b(o0); ov.y = f2b(o1); ov.z = f2b(o2); ov.w = f2b(o3);
      *(ushort4*)((unsigned short*)out + oi) = ov;
    }
  }
}

extern "C" void kernel_launch(void* const* d_in, const int* in_sizes, int n_in,
                              void* d_out, int out_size, void* d_ws, size_t ws_size,
                              hipStream_t stream) {
  const int N = in_sizes[0] / IN_DIM;
  const int E = in_sizes[1];

  const void* h   = d_in[0];
  const int* row  = (const int*)d_in[1];
  const int* col  = (const int*)d_in[2];
  const int* ety  = (const int*)d_in[3];
  const void* ee1 = d_in[4];
  const void* W1  = d_in[5];
  const void* Wr1 = d_in[6];
  const void* al1 = d_in[7];
  const void* ar1 = d_in[8];
  const void* ae1 = d_in[9];
  const void* ee2 = d_in[10];
  const void* W2  = d_in[11];
  const void* Wr2 = d_in[12];
  const void* al2 = d_in[13];
  const void* ar2 = d_in[14];
  const void* ae2 = d_in[15];
  const void* rW2 = d_in[16];
  const void* rb2 = d_in[17];

  char* p = (char*)d_ws;
  auto take = [&](size_t b) { char* q = p; p += (b + 255) & ~(size_t)255; return q; };
  unsigned short* h1   = (unsigned short*)take((size_t)N * 256 * 2);   // 25.6 MB
  unsigned short* emb1 = (unsigned short*)take((size_t)N * 256 * 2);   // 25.6 MB (layer2 aliases)
  int* srcc = (int*)take((size_t)E * 4);
  int* ptrb = (int*)take((size_t)(N + 1) * 4);
  int* cnt  = (int*)take((size_t)N * 4);
  int* bsum = (int*)take(1024);
  float* hl1 = (float*)take((size_t)N * 4 * 4);
  float* hr1 = (float*)take((size_t)N * 4 * 4);
  float* hl2 = (float*)take((size_t)N * 4);
  float* hr2 = (float*)take((size_t)N * 4);
  unsigned short* W1t = (unsigned short*)take(256 * 256 * 2);
  unsigned short* W2t = (unsigned short*)take(128 * 256 * 2);
  float* a2l = (float*)take(256 * 4);
  float* a2r = (float*)take(256 * 4);
  float* alD = (float*)take(256 * 4);
  float* arD = (float*)take(256 * 4);
  float* he1 = (float*)take(NT * 4 * 4);
  float* he2 = (float*)take(NT * 4);
  int* dflag = (int*)take(256);
  unsigned short* emb2 = emb1;                     // aliases dead emb1 after agg1
  unsigned short* res  = emb1 + (size_t)N * 64;

  const size_t need = (size_t)(p - (char*)d_ws);
  if (need > ws_size) {
    hipMemsetAsync(d_out, 0, (size_t)out_size * 2, stream);
    return;
  }

  const int ECB = (E + 1023) / 1024;
  const int MB = (N + 63) / 64;
  const int SB = (N + 255) / 256;
  const int AB = (N + 15) / 16;

  hipMemsetAsync(cnt, 0, (size_t)N * 4, stream);
  // prep + self-detect + edge count (one dispatch)
  prep_all_kernel<<<454 + ECB, 256, 0, stream>>>(
      W1, W2, rW2, al1, ar1, al2, ar2, ee1, Wr1, ae1, ee2, Wr2, ae2,
      W1t, W2t, a2l, a2r, he1, he2, alD, arD,
      (const unsigned int*)h, col, cnt, E, N, dflag);

  // CSR scan
  scan1_kernel<<<SB, 256, 0, stream>>>(cnt, ptrb, bsum, N);
  scan2_kernel<<<1, 256, 0, stream>>>(bsum, ptrb, SB, N);

  // CSR fill (first ECB blocks) + layer-1 GEMM co-resident in one dispatch
  gemm1_fill<<<ECB + MB, 256, 0, stream>>>(
      h, N, W1t, emb1, alD, arD, hl1, hr1, dflag, ECB,
      col, row, ety, ptrb, bsum, cnt, srcc, E);

  // layer-1 aggregation
  agg1_kernel<<<AB, 256, 0, stream>>>(
      ptrb, bsum, srcc, hl1, hr1, he1, emb1, h1, a2l, a2r, hl2, hr2, 0, N, E);

  // layer 2
  gemm2_fused<<<MB, 256, 0, stream>>>(h1, N, W2t, emb2, res, rb2, dflag);
  agg2_kernel<<<AB, 256, 0, stream>>>(
      ptrb, bsum, srcc, hl2, hr2, he2, emb2, res, d_out, N, E, dflag);
}

// Round 10
// 255.732 us; speedup vs baseline: 1.2714x; 1.0154x over previous
//
#include <hip/hip_runtime.h>
#include <hip/hip_bf16.h>

typedef __bf16 bf16x8 __attribute__((ext_vector_type(8)));
typedef float f32x4 __attribute__((ext_vector_type(4)));

#define IN_DIM 256
#define NT 8

__device__ __forceinline__ float b2f(unsigned short u) {
  union { unsigned int i; float f; } x; x.i = ((unsigned int)u) << 16; return x.f;
}
__device__ __forceinline__ float lo2f(unsigned int w) {
  union { unsigned int i; float f; } x; x.i = w << 16; return x.f;
}
__device__ __forceinline__ float hi2f(unsigned int w) {
  union { unsigned int i; float f; } x; x.i = w & 0xFFFF0000u; return x.f;
}
__device__ __forceinline__ unsigned short f2b(float f) {
  union { float f; unsigned int i; } u; u.f = f;
  unsigned int r = u.i + 0x7FFF + ((u.i >> 16) & 1);
  return (unsigned short)(r >> 16);
}
__device__ __forceinline__ unsigned int f2b2(float lo, float hi) {
  return (unsigned int)f2b(lo) | ((unsigned int)f2b(hi) << 16);
}
__device__ __forceinline__ float lrelu(float x) { return x >= 0.f ? x : 0.2f * x; }
__device__ __forceinline__ float ldf(const void* p, size_t i, int isf32) {
  return isf32 ? ((const float*)p)[i] : b2f(((const unsigned short*)p)[i]);
}

// ---------- fused prep: [0,384) W-transpose; [384,448) fold a2; [448,454) he/aD;
// [454, 454+ECB) edge count (4 edges/thread). Each prep block self-detects dtype. ----------
__global__ void prep_all_kernel(const void* __restrict__ W1, const void* __restrict__ W2,
                                const void* __restrict__ rW2,
                                const void* __restrict__ al1, const void* __restrict__ ar1,
                                const void* __restrict__ al2, const void* __restrict__ ar2,
                                const void* __restrict__ ee1, const void* __restrict__ Wr1,
                                const void* __restrict__ ae1,
                                const void* __restrict__ ee2, const void* __restrict__ Wr2,
                                const void* __restrict__ ae2,
                                unsigned short* __restrict__ W1t,
                                unsigned short* __restrict__ W2t,
                                float* __restrict__ a2l, float* __restrict__ a2r,
                                float* __restrict__ he1, float* __restrict__ he2,
                                float* __restrict__ alD, float* __restrict__ arD,
                                const unsigned int* __restrict__ hw,
                                const int* __restrict__ col, int* __restrict__ cnt,
                                int E_, int N_, int* __restrict__ dflag) {
  int b = blockIdx.x, tid = threadIdx.x;
  if (b >= 454) {
    // edge-count role (CSR histogram), 4 edges/thread
    int base = (b - 454) * 1024 + tid;
#pragma unroll
    for (int k = 0; k < 4; k++) {
      int e = base + k * 256;
      if (e < E_) {
        int c = col[e];
        if ((unsigned)c < (unsigned)N_) atomicAdd(&cnt[c], 1);
      }
    }
    return;
  }
  // self-detect dtype of h (wave 0 only, broadcast via LDS)
  __shared__ int sflag;
  {
    int bad = 0;
    if (tid < 64) {
      for (int i = 0; i < 4; i++) {
        unsigned int w = hw[tid * 4 + i];
        unsigned int ex = (w & 0x7FFFu) >> 7;
        if (ex >= 0xC0u) bad++;
      }
#pragma unroll
      for (int off = 32; off; off >>= 1) bad += __shfl_xor(bad, off);
      if (tid == 0) sflag = (bad > 8) ? 1 : 0;
    }
    __syncthreads();
  }
  const int isf32 = sflag;
  if (b == 0 && tid == 0) *dflag = isf32;
  if (b < 384) {
    int j = b, k = tid;
    if (j < 256) {
      int src = (j & 3) * 64 + (j >> 2);          // h*64+d
      W1t[j * 256 + k] = f2b(ldf(W1, (size_t)k * 256 + src, isf32));
    } else {
      int o = j - 256;
      float v = (o < 64) ? ldf(W2, (size_t)k * 64 + o, isf32)
                         : ldf(rW2, (size_t)k * 64 + (o - 64), isf32);
      W2t[o * 256 + k] = f2b(v);
    }
  } else if (b < 448) {
    int k = (b - 384) * 4 + (tid >> 6), d = tid & 63;
    float w2 = ldf(W2, (size_t)k * 64 + d, isf32);
    float l2 = w2 * ldf(al2, d, isf32);
    float r2 = w2 * ldf(ar2, d, isf32);
#pragma unroll
    for (int off = 32; off; off >>= 1) { l2 += __shfl_xor(l2, off); r2 += __shfl_xor(r2, off); }
    if (d == 0) { a2l[k] = l2; a2r[k] = r2; }
  } else {
    int bid = b - 448;
    int t = tid >> 5, d = tid & 31;
    if (bid < 4) {
      int h = bid;
      float s = 0.f;
#pragma unroll
      for (int e = 0; e < 32; e++)
        s += ldf(ee1, t * 32 + e, isf32) * ldf(Wr1, (size_t)(t * 32 + e) * 128 + h * 32 + d, isf32);
      float v = s * ldf(ae1, h * 32 + d, isf32);
#pragma unroll
      for (int off = 16; off; off >>= 1) v += __shfl_xor(v, off);
      if (d == 0) he1[t * 4 + h] = v;
    } else if (bid == 4) {
      float s = 0.f;
#pragma unroll
      for (int e = 0; e < 32; e++)
        s += ldf(ee2, t * 32 + e, isf32) * ldf(Wr2, (size_t)(t * 32 + e) * 32 + d, isf32);
      float v = s * ldf(ae2, d, isf32);
#pragma unroll
      for (int off = 16; off; off >>= 1) v += __shfl_xor(v, off);
      if (d == 0) he2[t] = v;
    } else {
      int j = tid;                       // D-major a vectors
      alD[j] = ldf(al1, (j & 3) * 64 + (j >> 2), isf32);
      arD[j] = ldf(ar1, (j & 3) * 64 + (j >> 2), isf32);
    }
  }
}

// ---------- L1 GEMM + CSR-fill (fill role FIRST, blocks [0,FillBlocks)).
// OCCUPANCY FIX: 32-row x 256-col block tile. Old 64-row tile needed acc[4][4]=64 AGPR
// + ~84 VGPR = ~148 regs/thread (unified file) -> hard 2-waves/SIMD cap (m69: waves
// halve at 128) = 8 waves/CU -- THAT was the 49us latency floor, not LDS or schedule
// (rounds 5/7/8/9 all failed around it). Now acc[2][4]=32 AGPR + ~75 VGPR <= 128 ->
// 4 waves/SIMD; LDS 40KB -> 4 blocks/CU = 16 waves/CU (2x latency cover). Cost: Bt
// staged 2x more (L2-resident, ~3-6us aggregate). No reg-dbuf (r9: -7us regression). ----------
__global__ __launch_bounds__(256, 4) void gemm1_fill(
    const void* __restrict__ A, int M,
    const unsigned short* __restrict__ Bt,      // W1t [256][256]
    unsigned short* __restrict__ emb1,
    const float* __restrict__ alD, const float* __restrict__ arD,
    float* __restrict__ hl1, float* __restrict__ hr1,
    const int* __restrict__ dflag, int FillBlocks,
    const int* __restrict__ col, const int* __restrict__ row,
    const int* __restrict__ ety, const int* __restrict__ ptrb,
    const int* __restrict__ bsum, int* __restrict__ cnt,
    int* __restrict__ srcc, int E_) {
  __shared__ unsigned short As[32 * 64];        // 4 KB
  __shared__ unsigned short Bs[256 * 64];       // 32 KB
  __shared__ float lsum[4][32][4];              // 2 KB
  __shared__ float rsum[4][32][4];              // 2 KB
  if (blockIdx.x < FillBlocks) {
    int base = blockIdx.x * 1024 + threadIdx.x;
#pragma unroll
    for (int k = 0; k < 4; k++) {
      int e = base + k * 256;
      if (e < E_) {
        int c = col[e];
        if ((unsigned)c < (unsigned)M) {
          int pos = atomicSub(&cnt[c], 1) - 1;
          long long slot = (long long)(ptrb[c] + bsum[c >> 8]) + pos;
          if (slot >= 0 && slot < E_) {
            int sr = row[e], t = ety[e];
            srcc[slot] = ((unsigned)sr < (unsigned)M && (unsigned)t < (unsigned)NT)
                             ? (sr | (t << 20)) : -1;
          }
        }
      }
    }
    return;
  }
  const int isf32 = *dflag;
  const int tid = threadIdx.x;
  const int m0 = (blockIdx.x - FillBlocks) * 32;
  const int wv = tid >> 6, lane = tid & 63;
  const int q = lane >> 4, m = lane & 15;
  const int jp = wv * 64;
  f32x4 acc[2][4] = {};
  for (int kc = 0; kc < 256; kc += 64) {
    {   // A stage: 32 rows x 64 cols; 1 int4 per thread
      int row_ = tid >> 3, qt = tid & 7;
      int gr = m0 + row_;
      int4 w;
      if (gr < M) {
        if (isf32) {
          const float* ap = (const float*)A + (size_t)gr * 256 + kc + qt * 8;
          float4 v0 = *(const float4*)ap;
          float4 v1 = *(const float4*)(ap + 4);
          w.x = (int)f2b2(v0.x, v0.y); w.y = (int)f2b2(v0.z, v0.w);
          w.z = (int)f2b2(v1.x, v1.y); w.w = (int)f2b2(v1.z, v1.w);
        } else {
          const unsigned short* ap = (const unsigned short*)A + (size_t)gr * 256 + kc + qt * 8;
          w = *(const int4*)ap;
        }
      } else {
        w.x = 0; w.y = 0; w.z = 0; w.w = 0;
      }
      int pg = qt ^ (row_ & 7);
      *(int4*)(As + row_ * 64 + pg * 8) = w;
    }
    {   // B stage: 256 rows x 64 cols; 8 int4 per thread
#pragma unroll
      for (int i = 0; i < 8; i++) {
        int id = tid + i * 256;
        int row_ = id >> 3, gg = id & 7;
        int4 v = *(const int4*)(Bt + (size_t)row_ * 256 + kc + gg * 8);
        int pg = gg ^ (row_ & 7);
        *(int4*)(Bs + row_ * 64 + pg * 8) = v;
      }
    }
    __syncthreads();
#pragma unroll
    for (int ks = 0; ks < 2; ks++) {
      int gk = ks * 4 + q;
      bf16x8 afr[2];
#pragma unroll
      for (int cm = 0; cm < 2; cm++) {
        int row_ = cm * 16 + m;
        afr[cm] = *(const bf16x8*)(As + row_ * 64 + (gk ^ (row_ & 7)) * 8);
      }
#pragma unroll
      for (int cj = 0; cj < 4; cj++) {
        int jr = jp + cj * 16 + m;
        bf16x8 b = *(const bf16x8*)(Bs + jr * 64 + (gk ^ (jr & 7)) * 8);
#pragma unroll
        for (int cm = 0; cm < 2; cm++)
          acc[cm][cj] = __builtin_amdgcn_mfma_f32_16x16x32_bf16(afr[cm], b, acc[cm][cj], 0, 0, 0);
      }
    }
    __syncthreads();
  }
  float al[4], ar[4];
#pragma unroll
  for (int cj = 0; cj < 4; cj++) {
    al[cj] = alD[jp + cj * 16 + m];
    ar[cj] = arD[jp + cj * 16 + m];
  }
#pragma unroll
  for (int cm = 0; cm < 2; cm++) {
#pragma unroll
    for (int r = 0; r < 4; r++) {
      int lrow = cm * 16 + q * 4 + r;
      int gm = m0 + lrow;
      float lp = 0.f, rp = 0.f;
#pragma unroll
      for (int cj = 0; cj < 4; cj++) {
        float v = acc[cm][cj][r];
        if (gm < M) emb1[(size_t)gm * 256 + jp + cj * 16 + m] = f2b(v);
        lp += v * al[cj]; rp += v * ar[cj];
      }
      lp += __shfl_xor(lp, 4); lp += __shfl_xor(lp, 8);
      rp += __shfl_xor(rp, 4); rp += __shfl_xor(rp, 8);
      if (m < 4) { lsum[wv][lrow][m] = lp; rsum[wv][lrow][m] = rp; }
    }
  }
  __syncthreads();
  if (tid < 128) {
    int row_ = tid >> 2, h = tid & 3;
    int gm = m0 + row_;
    if (gm < M) {
      float l = lsum[0][row_][h] + lsum[1][row_][h] + lsum[2][row_][h] + lsum[3][row_][h];
      float r = rsum[0][row_][h] + rsum[1][row_][h] + rsum[2][row_][h] + rsum[3][row_][h];
      hl1[(size_t)gm * 4 + h] = l;
      hr1[(size_t)gm * 4 + h] = r;
    }
  }
}

// ---------- L2 GEMM, 64-row tile (acc already 32 AGPR), 24KB LDS, 4 blocks/CU ----------
__global__ __launch_bounds__(256, 4) void gemm2_fused(
    const unsigned short* __restrict__ A, int M,
    const unsigned short* __restrict__ Bt,      // W2t [128][256]
    unsigned short* __restrict__ emb2, unsigned short* __restrict__ res,
    const void* __restrict__ bias, const int* __restrict__ dflag) {
  __shared__ unsigned short As[64 * 64];
  __shared__ unsigned short Bs[128 * 64];
  int isf32 = *dflag;
  const int tid = threadIdx.x;
  const int m0 = blockIdx.x * 64;
  const int wv = tid >> 6, lane = tid & 63;
  const int q = lane >> 4, m = lane & 15;
  const int jp = (wv & 1) * 64;
  const int mh = (wv >> 1) * 32;
  f32x4 acc[2][4] = {};
  for (int kc = 0; kc < 256; kc += 64) {
    {
      int row = tid >> 2, qt = tid & 3;
      int gr = m0 + row;
      unsigned short tmp[16];
      if (gr < M) {
        const unsigned short* ap = A + (size_t)gr * 256 + kc + qt * 16;
        *(int4*)tmp = *(const int4*)ap;
        *(int4*)(tmp + 8) = *(const int4*)(ap + 8);
      } else {
        for (int x = 0; x < 16; x++) tmp[x] = 0;
      }
      int g0 = (qt * 2) ^ (row & 7);
      int g1 = (qt * 2 + 1) ^ (row & 7);
      *(int4*)(As + row * 64 + g0 * 8) = *(int4*)tmp;
      *(int4*)(As + row * 64 + g1 * 8) = *(int4*)(tmp + 8);
    }
    {
#pragma unroll
      for (int i = 0; i < 4; i++) {
        int id = tid + i * 256;
        int row = id >> 3, gg = id & 7;
        int4 v = *(const int4*)(Bt + (size_t)row * 256 + kc + gg * 8);
        int pg = gg ^ (row & 7);
        *(int4*)(Bs + row * 64 + pg * 8) = v;
      }
    }
    __syncthreads();
#pragma unroll
    for (int ks = 0; ks < 2; ks++) {
      int gk = ks * 4 + q;
      bf16x8 afr[2];
#pragma unroll
      for (int cm = 0; cm < 2; cm++) {
        int row = mh + cm * 16 + m;
        afr[cm] = *(const bf16x8*)(As + row * 64 + (gk ^ (row & 7)) * 8);
      }
#pragma unroll
      for (int cj = 0; cj < 4; cj++) {
        int jr = jp + cj * 16 + m;
        bf16x8 b = *(const bf16x8*)(Bs + jr * 64 + (gk ^ (jr & 7)) * 8);
#pragma unroll
        for (int cm = 0; cm < 2; cm++)
          acc[cm][cj] = __builtin_amdgcn_mfma_f32_16x16x32_bf16(afr[cm], b, acc[cm][cj], 0, 0, 0);
      }
    }
    __syncthreads();
  }
  float bv[4];
#pragma unroll
  for (int cj = 0; cj < 4; cj++)
    bv[cj] = (jp == 64) ? ldf(bias, cj * 16 + m, isf32) : 0.f;
#pragma unroll
  for (int cm = 0; cm < 2; cm++) {
#pragma unroll
    for (int r = 0; r < 4; r++) {
      int gm = m0 + mh + cm * 16 + q * 4 + r;
      if (gm < M) {
#pragma unroll
        for (int cj = 0; cj < 4; cj++) {
          float v = acc[cm][cj][r];
          int gj = cj * 16 + m;
          if (jp == 0) emb2[(size_t)gm * 64 + gj] = f2b(v);
          else res[(size_t)gm * 64 + gj] = f2b(v + bv[cj]);
        }
      }
    }
  }
}

// ---------- CSR scan, single dispatch: block scan + last-block-finishes scan2.
// Device-scope visibility: bsum store -> __threadfence -> atomic ticket (rocPRIM
// decoupled pattern); last block re-reads bsum volatile. ----------
__global__ void scan1_kernel(const int* __restrict__ cnt, int* __restrict__ ptrb,
                             int* __restrict__ bsum, int* __restrict__ done,
                             int n, int nb) {
  __shared__ int wsum[4];
  __shared__ int lastflag;
  int tid = threadIdx.x, lane = tid & 63, wid = tid >> 6;
  if (tid == 0) lastflag = 0;
  int i = blockIdx.x * 256 + tid;
  int v = (i < n) ? cnt[i] : 0;
  int x = v;
#pragma unroll
  for (int off = 1; off < 64; off <<= 1) {
    int y = __shfl_up(x, off);
    if (lane >= off) x += y;
  }
  if (lane == 63) wsum[wid] = x;
  __syncthreads();
  int woff = 0;
#pragma unroll
  for (int k = 0; k < 4; k++) woff += (k < wid) ? wsum[k] : 0;
  if (i < n) ptrb[i] = x - v + woff;
  if (tid == 255) bsum[blockIdx.x] = woff + x;
  __syncthreads();
  if (tid == 255) {
    __threadfence();
    int t = atomicAdd(done, 1);
    if (t == (int)gridDim.x - 1) { __threadfence(); lastflag = 1; }
  }
  __syncthreads();
  if (lastflag) {
    int v2 = (tid < nb) ? ((volatile int*)bsum)[tid] : 0;
    int x2 = v2;
#pragma unroll
    for (int off = 1; off < 64; off <<= 1) {
      int y = __shfl_up(x2, off);
      if (lane >= off) x2 += y;
    }
    if (lane == 63) wsum[wid] = x2;
    __syncthreads();
    int woff2 = 0;
#pragma unroll
    for (int k = 0; k < 4; k++) woff2 += (k < wid) ? wsum[k] : 0;
    if (tid < nb) bsum[tid] = x2 - v2 + woff2;
    if (tid == 255) ptrb[n] = woff2 + x2;
  }
}

// ---------- layer-1 aggregation: 4 nodes per wave (16 lanes/node) ----------
// At its gather-BW floor (~3.2 TB/s across three structures) - hot loop untouched.
__global__ __launch_bounds__(256) void agg1_kernel(
    const int* __restrict__ ptrb, const int* __restrict__ bsumv,
    const int* __restrict__ srcc,
    const float* __restrict__ hl1, const float* __restrict__ hr1,
    const float* __restrict__ he1,
    const unsigned short* __restrict__ emb1, unsigned short* __restrict__ h1,
    const float* __restrict__ a2l, const float* __restrict__ a2r,
    float* __restrict__ hl2, float* __restrict__ hr2,
    int n0, int N_, int E_) {
  __shared__ float4 wds[4][64];
  __shared__ int sds[4][64];
  const int tid = threadIdx.x;
  const int wv = tid >> 6, lane = tid & 63;
  const int g = lane >> 4, ln = lane & 15;
  const int node = n0 + blockIdx.x * 16 + wv * 4 + g;
  const bool nv = node < N_;
  int p0 = 0, p1 = 0;
  if (nv) {
    p0 = ptrb[node] + bsumv[node >> 8];
    p1 = (node + 1 < N_) ? (ptrb[node + 1] + bsumv[(node + 1) >> 8]) : ptrb[N_];
    p0 = max(0, min(p0, E_)); p1 = max(p0, min(p1, E_));
  }
  float4 hrv = {0.f, 0.f, 0.f, 0.f};
  if (nv) hrv = *(const float4*)(hr1 + 4 * (size_t)node);
  float s0 = 0.f, s1 = 0.f, s2 = 0.f, s3 = 0.f;
  float acc[16];
#pragma unroll
  for (int k = 0; k < 16; k++) acc[k] = 0.f;
  const unsigned short* erow = emb1 + ln * 16;
  for (int pb = p0;; pb += 16) {
    if (!__any(pb < p1)) break;
    int mc = (pb < p1) ? min(p1 - pb, 16) : 0;
    float4 w = {0.f, 0.f, 0.f, 0.f};
    int src = 0;
    if (ln < mc) {
      int spk = srcc[pb + ln];
      if (spk >= 0) {
        int sr = spk & 0xFFFFF, t = spk >> 20;
        float4 a = *(const float4*)(hl1 + 4 * (size_t)sr);
        float4 ge = *(const float4*)(he1 + 4 * (size_t)t);
        w.x = __expf(lrelu(a.x + hrv.x + ge.x));
        w.y = __expf(lrelu(a.y + hrv.y + ge.y));
        w.z = __expf(lrelu(a.z + hrv.z + ge.z));
        w.w = __expf(lrelu(a.w + hrv.w + ge.w));
        src = sr;
      }
    }
    s0 += w.x; s1 += w.y; s2 += w.z; s3 += w.w;
    // per-wave LDS region; in-order wave execution keeps this coherent
    wds[wv][lane] = w;
    sds[wv][lane] = src;
    for (int j = 0; j < mc; j += 2) {
      bool v1 = (j + 1) < mc;
      float4 u0 = wds[wv][g * 16 + j];
      int r0 = sds[wv][g * 16 + j];
      const unsigned short* e0 = erow + (size_t)r0 * 256;
      int4 ra = *(const int4*)e0;
      int4 rb = *(const int4*)(e0 + 8);
      float4 u1; int4 rc, rd;
      if (v1) {
        u1 = wds[wv][g * 16 + j + 1];
        int r1 = sds[wv][g * 16 + j + 1];
        const unsigned short* e1 = erow + (size_t)r1 * 256;
        rc = *(const int4*)e1;
        rd = *(const int4*)(e1 + 8);
      }
      acc[0]  += u0.x * lo2f(ra.x); acc[1]  += u0.y * hi2f(ra.x);
      acc[2]  += u0.z * lo2f(ra.y); acc[3]  += u0.w * hi2f(ra.y);
      acc[4]  += u0.x * lo2f(ra.z); acc[5]  += u0.y * hi2f(ra.z);
      acc[6]  += u0.z * lo2f(ra.w); acc[7]  += u0.w * hi2f(ra.w);
      acc[8]  += u0.x * lo2f(rb.x); acc[9]  += u0.y * hi2f(rb.x);
      acc[10] += u0.z * lo2f(rb.y); acc[11] += u0.w * hi2f(rb.y);
      acc[12] += u0.x * lo2f(rb.z); acc[13] += u0.y * hi2f(rb.z);
      acc[14] += u0.z * lo2f(rb.w); acc[15] += u0.w * hi2f(rb.w);
      if (v1) {
        acc[0]  += u1.x * lo2f(rc.x); acc[1]  += u1.y * hi2f(rc.x);
        acc[2]  += u1.z * lo2f(rc.y); acc[3]  += u1.w * hi2f(rc.y);
        acc[4]  += u1.x * lo2f(rc.z); acc[5]  += u1.y * hi2f(rc.z);
        acc[6]  += u1.z * lo2f(rc.w); acc[7]  += u1.w * hi2f(rc.w);
        acc[8]  += u1.x * lo2f(rd.x); acc[9]  += u1.y * hi2f(rd.x);
        acc[10] += u1.z * lo2f(rd.y); acc[11] += u1.w * hi2f(rd.y);
        acc[12] += u1.x * lo2f(rd.z); acc[13] += u1.y * hi2f(rd.z);
        acc[14] += u1.z * lo2f(rd.w); acc[15] += u1.w * hi2f(rd.w);
      }
    }
  }
#pragma unroll
  for (int off = 1; off < 16; off <<= 1) {
    s0 += __shfl_xor(s0, off); s1 += __shfl_xor(s1, off);
    s2 += __shfl_xor(s2, off); s3 += __shfl_xor(s3, off);
  }
  float invs[4];
  invs[0] = s0 > 0.f ? 1.f / s0 : 0.f;
  invs[1] = s1 > 0.f ? 1.f / s1 : 0.f;
  invs[2] = s2 > 0.f ? 1.f / s2 : 0.f;
  invs[3] = s3 > 0.f ? 1.f / s3 : 0.f;
  float alv[16], arv[16];
#pragma unroll
  for (int q2 = 0; q2 < 4; q2++) {
    float4 t1 = *(const float4*)(a2l + ln * 16 + q2 * 4);
    float4 t2 = *(const float4*)(a2r + ln * 16 + q2 * 4);
    alv[q2 * 4 + 0] = t1.x; alv[q2 * 4 + 1] = t1.y;
    alv[q2 * 4 + 2] = t1.z; alv[q2 * 4 + 3] = t1.w;
    arv[q2 * 4 + 0] = t2.x; arv[q2 * 4 + 1] = t2.y;
    arv[q2 * 4 + 2] = t2.z; arv[q2 * 4 + 3] = t2.w;
  }
  float lp = 0.f, rp = 0.f;
  unsigned int ow[8];
#pragma unroll
  for (int k = 0; k < 16; k++) {
    float r = acc[k] * invs[k & 3];
    r = r > 0.f ? r : __expf(r) - 1.f;       // elu
    unsigned int bb = f2b(r);
    if ((k & 1) == 0) ow[k >> 1] = bb; else ow[k >> 1] |= bb << 16;
    lp += r * alv[k];
    rp += r * arv[k];
  }
  if (nv) {
    int4 va; va.x = ow[0]; va.y = ow[1]; va.z = ow[2]; va.w = ow[3];
    int4 vb; vb.x = ow[4]; vb.y = ow[5]; vb.z = ow[6]; vb.w = ow[7];
    *(int4*)(h1 + (size_t)node * 256 + ln * 16) = va;
    *(int4*)(h1 + (size_t)node * 256 + ln * 16 + 8) = vb;
  }
#pragma unroll
  for (int off = 1; off < 16; off <<= 1) {
    lp += __shfl_xor(lp, off); rp += __shfl_xor(rp, off);
  }
  if (nv && ln == 0) { hl2[node] = lp; hr2[node] = rp; }
}

// ---------- layer-2 aggregation: 4 nodes per wave (16 lanes/node), depth-1 prefetch ----------
__global__ __launch_bounds__(256) void agg2_kernel(
    const int* __restrict__ ptrb, const int* __restrict__ bsumv,
    const int* __restrict__ srcc,
    const float* __restrict__ hl2, const float* __restrict__ hr2,
    const float* __restrict__ he2,
    const unsigned short* __restrict__ emb2, const unsigned short* __restrict__ res,
    void* __restrict__ out, int N_, int E_, const int* __restrict__ dflag) {
  __shared__ int2 wsd[4][4][17];                 // padded: groups land on distinct banks
  const int isf32 = *dflag;
  const int tid = threadIdx.x;
  const int wv = tid >> 6, lane = tid & 63;
  const int g = lane >> 4, ln = lane & 15;
  const int node = blockIdx.x * 16 + wv * 4 + g;
  const bool nv = node < N_;
  int p0 = 0, p1 = 0;
  if (nv) {
    p0 = ptrb[node] + bsumv[node >> 8];
    p1 = (node + 1 < N_) ? (ptrb[node + 1] + bsumv[(node + 1) >> 8]) : ptrb[N_];
    p0 = max(0, min(p0, E_)); p1 = max(p0, min(p1, E_));
  }
  float hrv = nv ? hr2[node] : 0.f;
  float s = 0.f;
  float acc[4] = {0.f, 0.f, 0.f, 0.f};
  const unsigned short* erow = emb2 + ln * 4;
  for (int pb = p0;; pb += 16) {
    if (!__any(pb < p1)) break;
    int mc = (pb < p1) ? min(p1 - pb, 16) : 0;
    float w = 0.f; int src = 0;
    if (ln < mc) {
      int spk = srcc[pb + ln];
      if (spk >= 0) {
        int sr = spk & 0xFFFFF, t = spk >> 20;
        w = __expf(lrelu(hl2[sr] + hrv + he2[t]));
        src = sr;
      }
    }
    s += w;
    int2 pk; pk.x = __float_as_int(w); pk.y = src;
    wsd[wv][g][ln] = pk;
    // pipelined consume: issue loads for pair j+2 before FMAs of pair j
    int2 w0 = {0, 0}, w1 = {0, 0}; int2 pa = {0, 0}, pc = {0, 0};
    if (0 < mc) { w0 = wsd[wv][g][0]; pa = *(const int2*)(erow + (size_t)w0.y * 64); }
    if (1 < mc) { w1 = wsd[wv][g][1]; pc = *(const int2*)(erow + (size_t)w1.y * 64); }
    for (int j = 0; j < mc; j += 2) {
      int2 nw0 = {0, 0}, nw1 = {0, 0}, na = {0, 0}, nc = {0, 0};
      if (j + 2 < mc) { nw0 = wsd[wv][g][j + 2]; na = *(const int2*)(erow + (size_t)nw0.y * 64); }
      if (j + 3 < mc) { nw1 = wsd[wv][g][j + 3]; nc = *(const int2*)(erow + (size_t)nw1.y * 64); }
      float u0 = __int_as_float(w0.x);
      acc[0] += u0 * lo2f(pa.x); acc[1] += u0 * hi2f(pa.x);
      acc[2] += u0 * lo2f(pa.y); acc[3] += u0 * hi2f(pa.y);
      if (j + 1 < mc) {
        float u1 = __int_as_float(w1.x);
        acc[0] += u1 * lo2f(pc.x); acc[1] += u1 * hi2f(pc.x);
        acc[2] += u1 * lo2f(pc.y); acc[3] += u1 * hi2f(pc.y);
      }
      w0 = nw0; w1 = nw1; pa = na; pc = nc;
    }
  }
#pragma unroll
  for (int off = 1; off < 16; off <<= 1) s += __shfl_xor(s, off);
  float inv = s > 0.f ? 1.f / s : 0.f;
  if (nv) {
    ushort4 rv = *(const ushort4*)(res + (size_t)node * 64 + ln * 4);
    float o0 = acc[0] * inv + b2f(rv.x);
    float o1 = acc[1] * inv + b2f(rv.y);
    float o2 = acc[2] * inv + b2f(rv.z);
    float o3 = acc[3] * inv + b2f(rv.w);
    size_t oi = (size_t)node * 64 + ln * 4;
    if (isf32) {
      float4 ov = {o0, o1, o2, o3};
      *(float4*)((float*)out + oi) = ov;
    } else {
      ushort4 ov; ov.x = f2b(o0); ov.y = f2b(o1); ov.z = f2b(o2); ov.w = f2b(o3);
      *(ushort4*)((unsigned short*)out + oi) = ov;
    }
  }
}

extern "C" void kernel_launch(void* const* d_in, const int* in_sizes, int n_in,
                              void* d_out, int out_size, void* d_ws, size_t ws_size,
                              hipStream_t stream) {
  const int N = in_sizes[0] / IN_DIM;
  const int E = in_sizes[1];

  const void* h   = d_in[0];
  const int* row  = (const int*)d_in[1];
  const int* col  = (const int*)d_in[2];
  const int* ety  = (const int*)d_in[3];
  const void* ee1 = d_in[4];
  const void* W1  = d_in[5];
  const void* Wr1 = d_in[6];
  const void* al1 = d_in[7];
  const void* ar1 = d_in[8];
  const void* ae1 = d_in[9];
  const void* ee2 = d_in[10];
  const void* W2  = d_in[11];
  const void* Wr2 = d_in[12];
  const void* al2 = d_in[13];
  const void* ar2 = d_in[14];
  const void* ae2 = d_in[15];
  const void* rW2 = d_in[16];
  const void* rb2 = d_in[17];

  char* p = (char*)d_ws;
  auto take = [&](size_t b) { char* q = p; p += (b + 255) & ~(size_t)255; return q; };
  unsigned short* h1   = (unsigned short*)take((size_t)N * 256 * 2);   // 25.6 MB
  unsigned short* emb1 = (unsigned short*)take((size_t)N * 256 * 2);   // 25.6 MB (layer2 aliases)
  int* srcc = (int*)take((size_t)E * 4);
  int* ptrb = (int*)take((size_t)(N + 1) * 4);
  int* cnt  = (int*)take((size_t)(N + 64) * 4);   // [N] = done counter for merged scan
  int* bsum = (int*)take(1024);
  float* hl1 = (float*)take((size_t)N * 4 * 4);
  float* hr1 = (float*)take((size_t)N * 4 * 4);
  float* hl2 = (float*)take((size_t)N * 4);
  float* hr2 = (float*)take((size_t)N * 4);
  unsigned short* W1t = (unsigned short*)take(256 * 256 * 2);
  unsigned short* W2t = (unsigned short*)take(128 * 256 * 2);
  float* a2l = (float*)take(256 * 4);
  float* a2r = (float*)take(256 * 4);
  float* alD = (float*)take(256 * 4);
  float* arD = (float*)take(256 * 4);
  float* he1 = (float*)take(NT * 4 * 4);
  float* he2 = (float*)take(NT * 4);
  int* dflag = (int*)take(256);
  unsigned short* emb2 = emb1;                     // aliases dead emb1 after agg1
  unsigned short* res  = emb1 + (size_t)N * 64;
  int* done = cnt + N;

  const size_t need = (size_t)(p - (char*)d_ws);
  if (need > ws_size) {
    hipMemsetAsync(d_out, 0, (size_t)out_size * 2, stream);
    return;
  }

  const int ECB = (E + 1023) / 1024;
  const int MB32 = (N + 31) / 32;
  const int MB = (N + 63) / 64;
  const int SB = (N + 255) / 256;
  const int AB = (N + 15) / 16;

  hipMemsetAsync(cnt, 0, (size_t)(N + 64) * 4, stream);
  // prep + self-detect + edge count (one dispatch)
  prep_all_kernel<<<454 + ECB, 256, 0, stream>>>(
      W1, W2, rW2, al1, ar1, al2, ar2, ee1, Wr1, ae1, ee2, Wr2, ae2,
      W1t, W2t, a2l, a2r, he1, he2, alD, arD,
      (const unsigned int*)h, col, cnt, E, N, dflag);

  // CSR scan (scan2 folded into scan1 via last-block ticket)
  scan1_kernel<<<SB, 256, 0, stream>>>(cnt, ptrb, bsum, done, N, SB);

  // CSR fill (first ECB blocks) + layer-1 GEMM co-resident in one dispatch
  gemm1_fill<<<ECB + MB32, 256, 0, stream>>>(
      h, N, W1t, emb1, alD, arD, hl1, hr1, dflag, ECB,
      col, row, ety, ptrb, bsum, cnt, srcc, E);

  // layer-1 aggregation
  agg1_kernel<<<AB, 256, 0, stream>>>(
      ptrb, bsum, srcc, hl1, hr1, he1, emb1, h1, a2l, a2r, hl2, hr2, 0, N, E);

  // layer 2
  gemm2_fused<<<MB, 256, 0, stream>>>(h1, N, W2t, emb2, res, rb2, dflag);
  agg2_kernel<<<AB, 256, 0, stream>>>(
      ptrb, bsum, srcc, hl2, hr2, he2, emb2, res, d_out, N, E, dflag);
}